// Round 2
// baseline (683.292 us; speedup 1.0000x reference)
//
#include <hip/hip_runtime.h>

typedef unsigned short u16;
typedef __attribute__((ext_vector_type(8))) short bf16x8;   // 8 bf16 = 4 VGPRs
typedef __attribute__((ext_vector_type(4))) float f32x4;

#define EMBED 1024
#define FFDIM 4096
#define SEQ   2048
#define NTOK  8192

__device__ __forceinline__ u16 f2bf(float f) {              // RNE fp32->bf16
  union { float f; unsigned int u; } c; c.f = f;
  unsigned int r = ((c.u >> 16) & 1u) + 0x7fffu;
  return (u16)((c.u + r) >> 16);
}

__device__ __forceinline__ void gload16(const u16* g, u16* l) {
  __builtin_amdgcn_global_load_lds((const __attribute__((address_space(1))) void*)g,
                                   (__attribute__((address_space(3))) void*)l, 16, 0, 0);
}

// ---------------- fp32 [K][N] -> bf16 [N][K] (B^T layout for GEMM) -----------
__global__ __launch_bounds__(256) void wtrans(const float* __restrict__ W,
                                              u16* __restrict__ Wt, int K, int N) {
  __shared__ float tile[32][33];
  const int tx = threadIdx.x & 31, ty = threadIdx.x >> 5;
  const int n0 = blockIdx.x << 5, k0 = blockIdx.y << 5;
#pragma unroll
  for (int r = 0; r < 32; r += 8)
    tile[ty + r][tx] = W[(size_t)(k0 + ty + r) * N + n0 + tx];
  __syncthreads();
#pragma unroll
  for (int r = 0; r < 32; r += 8)
    Wt[(size_t)(n0 + ty + r) * K + k0 + tx] = f2bf(tile[tx][ty + r]);
}

// ---------------- V part of qkv [token][2048+h*64+d] -> Vt [bh*64+d][t] ------
__global__ __launch_bounds__(256) void vtrans(const u16* __restrict__ qkv,
                                              u16* __restrict__ Vt) {
  __shared__ u16 tile[32][33];
  const int tx = threadIdx.x & 31, ty = threadIdx.x >> 5;
  const int t0 = blockIdx.x << 5;
  const int rg0 = blockIdx.y << 5;            // global V row = bh*64 + d
  const int bh = rg0 >> 6, d0 = rg0 & 63;
  const int b = bh >> 4, h = bh & 15;
#pragma unroll
  for (int r = 0; r < 32; r += 8)
    tile[ty + r][tx] = qkv[(size_t)(b * SEQ + t0 + ty + r) * 3072 + 2048 + h * 64 + d0 + tx];
  __syncthreads();
#pragma unroll
  for (int r = 0; r < 32; r += 8)
    Vt[(size_t)(rg0 + ty + r) * SEQ + t0 + tx] = tile[tx][ty + r];
}

// ---------------- LayerNorm fp32 in -> bf16 out ------------------------------
__global__ __launch_bounds__(256) void ln_kernel(const float* __restrict__ xin,
                                                 const float* __restrict__ gamma,
                                                 const float* __restrict__ beta,
                                                 u16* __restrict__ out) {
  const int row = blockIdx.x, tid = threadIdx.x;
  const float4 v = reinterpret_cast<const float4*>(xin + (size_t)row * EMBED)[tid];
  float s  = v.x + v.y + v.z + v.w;
  float ss = v.x * v.x + v.y * v.y + v.z * v.z + v.w * v.w;
#pragma unroll
  for (int m = 1; m < 64; m <<= 1) { s += __shfl_xor(s, m); ss += __shfl_xor(ss, m); }
  __shared__ float red[8];
  if ((tid & 63) == 0) { red[tid >> 6] = s; red[4 + (tid >> 6)] = ss; }
  __syncthreads();
  s  = red[0] + red[1] + red[2] + red[3];
  ss = red[4] + red[5] + red[6] + red[7];
  const float mean = s * (1.0f / EMBED);
  const float var  = ss * (1.0f / EMBED) - mean * mean;
  const float rstd = rsqrtf(var + 1e-5f);
  const float4 g  = reinterpret_cast<const float4*>(gamma)[tid];
  const float4 bb = reinterpret_cast<const float4*>(beta)[tid];
  ushort4 o;
  o.x = f2bf((v.x - mean) * rstd * g.x + bb.x);
  o.y = f2bf((v.y - mean) * rstd * g.y + bb.y);
  o.z = f2bf((v.z - mean) * rstd * g.z + bb.z);
  o.w = f2bf((v.w - mean) * rstd * g.w + bb.w);
  reinterpret_cast<ushort4*>(out + (size_t)row * EMBED)[tid] = o;
}

// ---------------- bf16 GEMM, A [M][K] x Bt [N][K] -> C [M][N] ----------------
// EPI 0: store bf16 | 1: +bias +res -> fp32 | 2: +bias, GELU -> bf16
template <int EPI>
__global__ __launch_bounds__(256) void gemm_bt(const u16* __restrict__ A,
                                               const u16* __restrict__ Bt,
                                               void* __restrict__ Cv,
                                               const float* __restrict__ bias,
                                               const float* __restrict__ res,
                                               int M, int N, int K) {
  __shared__ __align__(16) u16 As[128 * 64];   // [row][k], XOR-swizzled
  __shared__ __align__(16) u16 Bs[128 * 64];   // [col][k], XOR-swizzled
  const int tid = threadIdx.x;
  const int lane = tid & 63, wid = tid >> 6;
  const int l4 = lane >> 4, l15 = lane & 15;
  const int wr = wid >> 1, wc = wid & 1;
  const int brow = blockIdx.y << 7, bcol = blockIdx.x << 7;

  const f32x4 z4 = {0.f, 0.f, 0.f, 0.f};
  f32x4 acc[4][4];
#pragma unroll
  for (int m = 0; m < 4; ++m)
#pragma unroll
    for (int n = 0; n < 4; ++n) acc[m][n] = z4;

  const int srow = tid >> 3;
  const int srck = ((tid & 7) << 4) ^ ((srow & 7) << 4);
  const u16* gA = A  + (size_t)(brow + srow) * K + (srck >> 1);
  const u16* gB = Bt + (size_t)(bcol + srow) * K + (srck >> 1);

  const int nk = K >> 6;
  for (int kt = 0; kt < nk; ++kt) {
    __syncthreads();
#pragma unroll
    for (int p = 0; p < 4; ++p) {
      gload16(gA + (size_t)p * 32 * K, &As[(p * 256 + wid * 64) * 8]);
      gload16(gB + (size_t)p * 32 * K, &Bs[(p * 256 + wid * 64) * 8]);
    }
    gA += 64; gB += 64;
    __syncthreads();
#pragma unroll
    for (int ks = 0; ks < 2; ++ks) {
      bf16x8 af[4], bfr[4];
      const int kk = ks * 32 + (l4 << 3);
#pragma unroll
      for (int m = 0; m < 4; ++m) {
        const int r = wr * 64 + m * 16 + l15;
        af[m] = *(const bf16x8*)&As[r * 64 + (kk ^ ((r & 7) << 3))];
      }
#pragma unroll
      for (int n = 0; n < 4; ++n) {
        const int r = wc * 64 + n * 16 + l15;
        bfr[n] = *(const bf16x8*)&Bs[r * 64 + (kk ^ ((r & 7) << 3))];
      }
#pragma unroll
      for (int m = 0; m < 4; ++m)
#pragma unroll
        for (int n = 0; n < 4; ++n)
          acc[m][n] = __builtin_amdgcn_mfma_f32_16x16x32_bf16(af[m], bfr[n], acc[m][n], 0, 0, 0);
    }
  }

  // C/D layout (verified): col = lane&15, row = (lane>>4)*4 + reg
  const int rowb = brow + wr * 64 + (l4 << 2);
  const int colb = bcol + wc * 64 + l15;
#pragma unroll
  for (int n = 0; n < 4; ++n) {
    const int col = colb + n * 16;
    float bv = 0.f;
    if (EPI != 0) bv = bias[col];
#pragma unroll
    for (int m = 0; m < 4; ++m) {
#pragma unroll
      for (int j = 0; j < 4; ++j) {
        const int row = rowb + m * 16 + j;
        const float v = acc[m][n][j];
        if (EPI == 0) {
          ((u16*)Cv)[(size_t)row * N + col] = f2bf(v);
        } else if (EPI == 1) {
          ((float*)Cv)[(size_t)row * N + col] = v + bv + res[(size_t)row * N + col];
        } else {
          const float t = v + bv;
          const float gl = 0.5f * t * (1.0f + erff(t * 0.70710678118654752f));
          ((u16*)Cv)[(size_t)row * N + col] = f2bf(gl);
        }
      }
    }
  }
}

// ---------------- causal flash attention v2 ----------------------------------
// 4 waves x 16 q-rows, KVBLK=64, swapped QK^T (S^T in regs, per-lane softmax),
// T14 async staging (load next K/V to regs during compute).
__global__ __launch_bounds__(256) void attn_fwd(const u16* __restrict__ qkv,
                                                const u16* __restrict__ Vt,
                                                u16* __restrict__ attn) {
  __shared__ __align__(16) u16 Ks[64 * 72];       // [kv][d], pad 8
  __shared__ __align__(16) u16 Vs[64 * 72];       // [d][kv], pad 8
  __shared__ __align__(16) u16 Ps[4 * 16 * 72];   // per-wave P [q][kv], pad 8
  __shared__ float Bx[4][16];                     // per-wave sc broadcast
  __shared__ float Bl[4][16];                     // per-wave lrun broadcast
  const int tid = threadIdx.x, lane = tid & 63, wid = tid >> 6;
  const int l4 = lane >> 4, l15 = lane & 15;
  const int qb = ((int)gridDim.x - 1 - (int)blockIdx.x) << 6;  // heavy blocks first
  const int bh = blockIdx.y, b = bh >> 4, h = bh & 15;
  const size_t bt0 = (size_t)b * SEQ;

  const int qw = qb + wid * 16;                   // wave's first q row
  const int qlane = qw + l15;                     // this lane's q row (S^T col)
  const int wqhi = qw + 15;

  // Q B-fragments: lane holds Q[q=l15][d = l4*8 + 0..7 (+32)]
  const u16* qptr = qkv + (bt0 + qlane) * 3072 + h * 64 + (l4 << 3);
  const bf16x8 aq0 = *(const bf16x8*)qptr;
  const bf16x8 aq1 = *(const bf16x8*)(qptr + 32);

  const f32x4 z4 = {0.f, 0.f, 0.f, 0.f};
  f32x4 o[4]; o[0] = z4; o[1] = z4; o[2] = z4; o[3] = z4;
  float mrun = -1e30f, lrun = 0.f;

  // staging: 64 rows x 8 chunks(16B) per array; thread does 2 chunks of each
  const int sr = tid >> 2;                        // row 0..63
  const int sc0 = (tid & 3) << 4;                 // u16 col of first chunk pair
  const u16* kbase = qkv + bt0 * 3072 + 1024 + h * 64;
  const u16* vbase = Vt + (size_t)bh * 64 * SEQ;

  // prologue: preload j0 = 0
  bf16x8 kp0 = *(const bf16x8*)(kbase + (size_t)sr * 3072 + sc0);
  bf16x8 kp1 = *(const bf16x8*)(kbase + (size_t)sr * 3072 + sc0 + 8);
  bf16x8 vp0 = *(const bf16x8*)(vbase + (size_t)sr * SEQ + sc0);
  bf16x8 vp1 = *(const bf16x8*)(vbase + (size_t)sr * SEQ + sc0 + 8);

  for (int j0 = 0; j0 <= qb; j0 += 64) {
    __syncthreads();                              // prev-iter LDS reads done
    *(bf16x8*)&Ks[sr * 72 + sc0]     = kp0;
    *(bf16x8*)&Ks[sr * 72 + sc0 + 8] = kp1;
    *(bf16x8*)&Vs[sr * 72 + sc0]     = vp0;
    *(bf16x8*)&Vs[sr * 72 + sc0 + 8] = vp1;
    __syncthreads();

    if (j0 + 64 <= qb) {                          // T14: issue next-tile loads now
      const size_t kro = (size_t)(j0 + 64 + sr);
      kp0 = *(const bf16x8*)(kbase + kro * 3072 + sc0);
      kp1 = *(const bf16x8*)(kbase + kro * 3072 + sc0 + 8);
      vp0 = *(const bf16x8*)(vbase + (size_t)sr * SEQ + j0 + 64 + sc0);
      vp1 = *(const bf16x8*)(vbase + (size_t)sr * SEQ + j0 + 64 + sc0 + 8);
    }

    const int nt4 = min(4, ((wqhi - j0) >> 4) + 1);  // active 16-kv tiles

    // QK^T swapped: S^T[kv = l4*4+j][q = l15] per tile
    f32x4 s[4];
#pragma unroll
    for (int t = 0; t < 4; ++t) {
      if (t < nt4) {
        const bf16x8 ak0 = *(const bf16x8*)&Ks[(t * 16 + l15) * 72 + (l4 << 3)];
        const bf16x8 ak1 = *(const bf16x8*)&Ks[(t * 16 + l15) * 72 + 32 + (l4 << 3)];
        f32x4 a = z4;
        a = __builtin_amdgcn_mfma_f32_16x16x32_bf16(ak0, aq0, a, 0, 0, 0);
        a = __builtin_amdgcn_mfma_f32_16x16x32_bf16(ak1, aq1, a, 0, 0, 0);
        s[t] = a;
      }
    }

    // per-lane softmax over kv (q = l15 fixed per lane)
    float mt = -1e30f;
#pragma unroll
    for (int t = 0; t < 4; ++t) {
      if (t < nt4) {
        const int kvb = j0 + t * 16 + (l4 << 2);
#pragma unroll
        for (int j = 0; j < 4; ++j) {
          const float v = (kvb + j > qlane) ? -1e30f : s[t][j] * 0.125f;
          s[t][j] = v;
          mt = fmaxf(mt, v);
        }
      }
    }
    mt = fmaxf(mt, __shfl_xor(mt, 16));
    mt = fmaxf(mt, __shfl_xor(mt, 32));
    const float mn = fmaxf(mrun, mt);
    const float sc = __expf(mrun - mn);
    mrun = mn;
    float ls = 0.f;
#pragma unroll
    for (int t = 0; t < 4; ++t) {
      if (t < nt4) {
#pragma unroll
        for (int j = 0; j < 4; ++j) {
          const float e = __expf(s[t][j] - mn);
          s[t][j] = e;
          ls += e;
        }
      }
    }
    ls += __shfl_xor(ls, 16);
    ls += __shfl_xor(ls, 32);
    lrun = lrun * sc + ls;
    if (l4 == 0) Bx[wid][l15] = sc;

    // P -> LDS [q][kv], packed 4 kv per 8B store
#pragma unroll
    for (int t = 0; t < 4; ++t) {
      ushort4 pk;
      if (t < nt4) {
        pk.x = f2bf(s[t][0]); pk.y = f2bf(s[t][1]);
        pk.z = f2bf(s[t][2]); pk.w = f2bf(s[t][3]);
      } else {
        pk.x = 0; pk.y = 0; pk.z = 0; pk.w = 0;
      }
      *(ushort4*)&Ps[wid * 1152 + l15 * 72 + t * 16 + (l4 << 2)] = pk;
    }

    // rescale O (O layout: row q = l4*4+j, col d = l15)
    const f32x4 sc4 = *(const f32x4*)&Bx[wid][l4 << 2];
#pragma unroll
    for (int dt = 0; dt < 4; ++dt)
#pragma unroll
      for (int j = 0; j < 4; ++j) o[dt][j] *= sc4[j];

    // PV: A = P[q=l15][kv slots], B = V[kv slots][d=l15] from Vs[d][kv]
    const bf16x8 ap0 = *(const bf16x8*)&Ps[wid * 1152 + l15 * 72 + (l4 << 3)];
    const bf16x8 ap1 = *(const bf16x8*)&Ps[wid * 1152 + l15 * 72 + 32 + (l4 << 3)];
#pragma unroll
    for (int dt = 0; dt < 4; ++dt) {
      const bf16x8 bv0 = *(const bf16x8*)&Vs[(dt * 16 + l15) * 72 + (l4 << 3)];
      const bf16x8 bv1 = *(const bf16x8*)&Vs[(dt * 16 + l15) * 72 + 32 + (l4 << 3)];
      o[dt] = __builtin_amdgcn_mfma_f32_16x16x32_bf16(ap0, bv0, o[dt], 0, 0, 0);
      o[dt] = __builtin_amdgcn_mfma_f32_16x16x32_bf16(ap1, bv1, o[dt], 0, 0, 0);
    }
  }

  if (l4 == 0) Bl[wid][l15] = lrun;
  const f32x4 lr4 = *(const f32x4*)&Bl[wid][l4 << 2];
  const size_t rowt = bt0 + qw + (l4 << 2);
#pragma unroll
  for (int dt = 0; dt < 4; ++dt) {
    const int col = h * 64 + dt * 16 + l15;
#pragma unroll
    for (int j = 0; j < 4; ++j)
      attn[(rowt + j) * EMBED + col] = f2bf(o[dt][j] / lr4[j]);
  }
}

// ---------------- driver ------------------------------------------------------
extern "C" void kernel_launch(void* const* d_in, const int* in_sizes, int n_in,
                              void* d_out, int out_size, void* d_ws, size_t ws_size,
                              hipStream_t stream) {
  const float* x   = (const float*)d_in[0];
  const float* Wq  = (const float*)d_in[1];
  const float* Wk  = (const float*)d_in[2];
  const float* Wv  = (const float*)d_in[3];
  const float* Wo  = (const float*)d_in[4];
  const float* bo  = (const float*)d_in[5];
  const float* W1  = (const float*)d_in[6];
  const float* b1  = (const float*)d_in[7];
  const float* W2  = (const float*)d_in[8];
  const float* b2  = (const float*)d_in[9];
  const float* g1  = (const float*)d_in[10];
  const float* be1 = (const float*)d_in[11];
  const float* g2  = (const float*)d_in[12];
  const float* be2 = (const float*)d_in[13];

  char* ws = (char*)d_ws;
  u16* wqkv_t = (u16*)(ws + 0);                 // [3072][1024] bf16   6 MB
  u16* wo_t   = (u16*)(ws + 6291456);           // [1024][1024]        2 MB
  u16* w1_t   = (u16*)(ws + 8388608);           // [4096][1024]        8 MB
  u16* w2_t   = (u16*)(ws + 16777216);          // [1024][4096]        8 MB
  u16* hbuf   = (u16*)(ws + 25165824);          // LN out, reused     16 MB
  u16* qkv    = (u16*)(ws + 41943040);          // [8192][3072]       48 MB
  u16* ff1    = (u16*)(ws + 41943040);          // overlaps qkv+Vt    64 MB
  u16* vt     = (u16*)(ws + 92274688);          // [64*64][2048]      16 MB
  u16* attnb  = (u16*)(ws + 109051904);         // [8192][1024]       16 MB
  float* x2   = (float*)(ws + 125829120);       // fp32 residual      32 MB
  float* outp = (float*)d_out;

  dim3 blk(256);
  wtrans<<<dim3(32, 32),  blk, 0, stream>>>(Wq, wqkv_t,               1024, 1024);
  wtrans<<<dim3(32, 32),  blk, 0, stream>>>(Wk, wqkv_t + 1024 * 1024, 1024, 1024);
  wtrans<<<dim3(32, 32),  blk, 0, stream>>>(Wv, wqkv_t + 2048 * 1024, 1024, 1024);
  wtrans<<<dim3(32, 32),  blk, 0, stream>>>(Wo, wo_t,                 1024, 1024);
  wtrans<<<dim3(128, 32), blk, 0, stream>>>(W1, w1_t,                 1024, 4096);
  wtrans<<<dim3(32, 128), blk, 0, stream>>>(W2, w2_t,                 4096, 1024);

  ln_kernel<<<dim3(8192), blk, 0, stream>>>(x, g1, be1, hbuf);
  gemm_bt<0><<<dim3(24, 64), blk, 0, stream>>>(hbuf, wqkv_t, qkv, nullptr, nullptr,
                                               8192, 3072, 1024);
  vtrans<<<dim3(64, 128), blk, 0, stream>>>(qkv, vt);
  attn_fwd<<<dim3(32, 64), blk, 0, stream>>>(qkv, vt, attnb);
  gemm_bt<1><<<dim3(8, 64), blk, 0, stream>>>(attnb, wo_t, x2, bo, x,
                                              8192, 1024, 1024);
  ln_kernel<<<dim3(8192), blk, 0, stream>>>(x2, g2, be2, hbuf);
  gemm_bt<2><<<dim3(32, 64), blk, 0, stream>>>(hbuf, w1_t, ff1, b1, nullptr,
                                               8192, 4096, 1024);
  gemm_bt<1><<<dim3(8, 64), blk, 0, stream>>>(ff1, w2_t, outp, b2, x2,
                                              8192, 1024, 4096);
}

// Round 3
// 550.766 us; speedup vs baseline: 1.2406x; 1.2406x over previous
//
#include <hip/hip_runtime.h>

typedef unsigned short u16;
typedef __attribute__((ext_vector_type(8))) short bf16x8;   // 8 bf16 = 4 VGPRs
typedef __attribute__((ext_vector_type(4))) float f32x4;

#define EMBED 1024
#define FFDIM 4096
#define SEQ   2048
#define NTOK  8192
#define ATT_C 0.18033688011112042f   // 0.125 * log2(e)

__device__ __forceinline__ u16 f2bf(float f) {              // RNE fp32->bf16
  union { float f; unsigned int u; } c; c.f = f;
  unsigned int r = ((c.u >> 16) & 1u) + 0x7fffu;
  return (u16)((c.u + r) >> 16);
}

__device__ __forceinline__ unsigned cvtpk(float lo, float hi) {
  unsigned r;
  asm("v_cvt_pk_bf16_f32 %0, %1, %2" : "=v"(r) : "v"(lo), "v"(hi));
  return r;
}

__device__ __forceinline__ void gload16(const u16* g, u16* l) {
  __builtin_amdgcn_global_load_lds((const __attribute__((address_space(1))) void*)g,
                                   (__attribute__((address_space(3))) void*)l, 16, 0, 0);
}

// ---------------- fp32 [K][N] -> bf16 [N][K] (B^T layout for GEMM) -----------
__global__ __launch_bounds__(256) void wtrans(const float* __restrict__ W,
                                              u16* __restrict__ Wt, int K, int N) {
  __shared__ float tile[32][33];
  const int tx = threadIdx.x & 31, ty = threadIdx.x >> 5;
  const int n0 = blockIdx.x << 5, k0 = blockIdx.y << 5;
#pragma unroll
  for (int r = 0; r < 32; r += 8)
    tile[ty + r][tx] = W[(size_t)(k0 + ty + r) * N + n0 + tx];
  __syncthreads();
#pragma unroll
  for (int r = 0; r < 32; r += 8)
    Wt[(size_t)(n0 + ty + r) * K + k0 + tx] = f2bf(tile[tx][ty + r]);
}

// ---------------- V part of qkv [token][2048+h*64+d] -> Vt [bh*64+d][t] ------
__global__ __launch_bounds__(256) void vtrans(const u16* __restrict__ qkv,
                                              u16* __restrict__ Vt) {
  __shared__ u16 tile[32][33];
  const int tx = threadIdx.x & 31, ty = threadIdx.x >> 5;
  const int t0 = blockIdx.x << 5;
  const int rg0 = blockIdx.y << 5;            // global V row = bh*64 + d
  const int bh = rg0 >> 6, d0 = rg0 & 63;
  const int b = bh >> 4, h = bh & 15;
#pragma unroll
  for (int r = 0; r < 32; r += 8)
    tile[ty + r][tx] = qkv[(size_t)(b * SEQ + t0 + ty + r) * 3072 + 2048 + h * 64 + d0 + tx];
  __syncthreads();
#pragma unroll
  for (int r = 0; r < 32; r += 8)
    Vt[(size_t)(rg0 + ty + r) * SEQ + t0 + tx] = tile[tx][ty + r];
}

// ---------------- LayerNorm fp32 in -> bf16 out ------------------------------
__global__ __launch_bounds__(256) void ln_kernel(const float* __restrict__ xin,
                                                 const float* __restrict__ gamma,
                                                 const float* __restrict__ beta,
                                                 u16* __restrict__ out) {
  const int row = blockIdx.x, tid = threadIdx.x;
  const float4 v = reinterpret_cast<const float4*>(xin + (size_t)row * EMBED)[tid];
  float s  = v.x + v.y + v.z + v.w;
  float ss = v.x * v.x + v.y * v.y + v.z * v.z + v.w * v.w;
#pragma unroll
  for (int m = 1; m < 64; m <<= 1) { s += __shfl_xor(s, m); ss += __shfl_xor(ss, m); }
  __shared__ float red[8];
  if ((tid & 63) == 0) { red[tid >> 6] = s; red[4 + (tid >> 6)] = ss; }
  __syncthreads();
  s  = red[0] + red[1] + red[2] + red[3];
  ss = red[4] + red[5] + red[6] + red[7];
  const float mean = s * (1.0f / EMBED);
  const float var  = ss * (1.0f / EMBED) - mean * mean;
  const float rstd = rsqrtf(var + 1e-5f);
  const float4 g  = reinterpret_cast<const float4*>(gamma)[tid];
  const float4 bb = reinterpret_cast<const float4*>(beta)[tid];
  ushort4 o;
  o.x = f2bf((v.x - mean) * rstd * g.x + bb.x);
  o.y = f2bf((v.y - mean) * rstd * g.y + bb.y);
  o.z = f2bf((v.z - mean) * rstd * g.z + bb.z);
  o.w = f2bf((v.w - mean) * rstd * g.w + bb.w);
  reinterpret_cast<ushort4*>(out + (size_t)row * EMBED)[tid] = o;
}

// ---------------- bf16 GEMM, A [M][K] x Bt [N][K] -> C [M][N] ----------------
// EPI 0: store bf16 | 1: +bias +res -> fp32 | 2: +bias, GELU -> bf16
template <int EPI>
__global__ __launch_bounds__(256) void gemm_bt(const u16* __restrict__ A,
                                               const u16* __restrict__ Bt,
                                               void* __restrict__ Cv,
                                               const float* __restrict__ bias,
                                               const float* __restrict__ res,
                                               int M, int N, int K) {
  __shared__ __align__(16) u16 As[128 * 64];   // [row][k], XOR-swizzled
  __shared__ __align__(16) u16 Bs[128 * 64];   // [col][k], XOR-swizzled
  const int tid = threadIdx.x;
  const int lane = tid & 63, wid = tid >> 6;
  const int l4 = lane >> 4, l15 = lane & 15;
  const int wr = wid >> 1, wc = wid & 1;
  const int brow = blockIdx.y << 7, bcol = blockIdx.x << 7;

  const f32x4 z4 = {0.f, 0.f, 0.f, 0.f};
  f32x4 acc[4][4];
#pragma unroll
  for (int m = 0; m < 4; ++m)
#pragma unroll
    for (int n = 0; n < 4; ++n) acc[m][n] = z4;

  const int srow = tid >> 3;
  const int srck = ((tid & 7) << 4) ^ ((srow & 7) << 4);
  const u16* gA = A  + (size_t)(brow + srow) * K + (srck >> 1);
  const u16* gB = Bt + (size_t)(bcol + srow) * K + (srck >> 1);

  const int nk = K >> 6;
  for (int kt = 0; kt < nk; ++kt) {
    __syncthreads();
#pragma unroll
    for (int p = 0; p < 4; ++p) {
      gload16(gA + (size_t)p * 32 * K, &As[(p * 256 + wid * 64) * 8]);
      gload16(gB + (size_t)p * 32 * K, &Bs[(p * 256 + wid * 64) * 8]);
    }
    gA += 64; gB += 64;
    __syncthreads();
#pragma unroll
    for (int ks = 0; ks < 2; ++ks) {
      bf16x8 af[4], bfr[4];
      const int kk = ks * 32 + (l4 << 3);
#pragma unroll
      for (int m = 0; m < 4; ++m) {
        const int r = wr * 64 + m * 16 + l15;
        af[m] = *(const bf16x8*)&As[r * 64 + (kk ^ ((r & 7) << 3))];
      }
#pragma unroll
      for (int n = 0; n < 4; ++n) {
        const int r = wc * 64 + n * 16 + l15;
        bfr[n] = *(const bf16x8*)&Bs[r * 64 + (kk ^ ((r & 7) << 3))];
      }
#pragma unroll
      for (int m = 0; m < 4; ++m)
#pragma unroll
        for (int n = 0; n < 4; ++n)
          acc[m][n] = __builtin_amdgcn_mfma_f32_16x16x32_bf16(af[m], bfr[n], acc[m][n], 0, 0, 0);
    }
  }

  // C/D layout (verified): col = lane&15, row = (lane>>4)*4 + reg
  const int rowb = brow + wr * 64 + (l4 << 2);
  const int colb = bcol + wc * 64 + l15;
#pragma unroll
  for (int n = 0; n < 4; ++n) {
    const int col = colb + n * 16;
    float bv = 0.f;
    if (EPI != 0) bv = bias[col];
#pragma unroll
    for (int m = 0; m < 4; ++m) {
#pragma unroll
      for (int j = 0; j < 4; ++j) {
        const int row = rowb + m * 16 + j;
        const float v = acc[m][n][j];
        if (EPI == 0) {
          ((u16*)Cv)[(size_t)row * N + col] = f2bf(v);
        } else if (EPI == 1) {
          ((float*)Cv)[(size_t)row * N + col] = v + bv + res[(size_t)row * N + col];
        } else {
          const float t = v + bv;
          const float gl = 0.5f * t * (1.0f + erff(t * 0.70710678118654752f));
          ((u16*)Cv)[(size_t)row * N + col] = f2bf(gl);
        }
      }
    }
  }
}

// ---------------- causal flash attention v3 ----------------------------------
// 4 waves x 32 q-rows (128 q/block), KVBLK=64. Swapped QK^T -> S^T (q=lane&15),
// O^T accumulation (lane-local softmax state), exp2-domain softmax, cvt_pk P
// packing, chunk-skipped PV, T14 reg-prefetch of K/V, LDS-bounced output.
__global__ __launch_bounds__(256) void attn_fwd(const u16* __restrict__ qkv,
                                                const u16* __restrict__ Vt,
                                                u16* __restrict__ attn) {
  __shared__ __align__(16) u16 Ks[64 * 72];       // [kv][d], pad 8
  __shared__ __align__(16) u16 Vs[64 * 72];       // [d][kv], pad 8
  __shared__ __align__(16) u16 Ps[4 * 32 * 72];   // per-wave P^T-source [q][kv]
  const int tid = threadIdx.x, lane = tid & 63, wid = tid >> 6;
  const int l4 = lane >> 4, l15 = lane & 15;
  const int Qb = ((int)gridDim.x - 1 - (int)blockIdx.x) << 7;  // heavy first
  const int bh = blockIdx.y, b = bh >> 4, h = bh & 15;
  const size_t bt0 = (size_t)b * SEQ;
  const int qw = Qb + wid * 32;                   // wave's first q row
  u16* Pw = &Ps[wid * 32 * 72];

  // Q fragments (B-frag): lane holds Q[q = qw+16qt+l15][d = l4*8.. , +32]
  bf16x8 aq[2][2];
#pragma unroll
  for (int qt = 0; qt < 2; ++qt) {
    const u16* qp = qkv + (bt0 + qw + qt * 16 + l15) * 3072 + h * 64 + (l4 << 3);
    aq[qt][0] = *(const bf16x8*)qp;
    aq[qt][1] = *(const bf16x8*)(qp + 32);
  }

  const f32x4 z4 = {0.f, 0.f, 0.f, 0.f};
  f32x4 o[2][4];                                  // O^T: row d=dt*16+l4*4+j, col q=l15
#pragma unroll
  for (int qt = 0; qt < 2; ++qt)
#pragma unroll
    for (int dt = 0; dt < 4; ++dt) o[qt][dt] = z4;
  float mrun[2] = {-1e30f, -1e30f}, lrun[2] = {0.f, 0.f};

  // staging: 64 rows x 8 chunks(16B); each thread 2 chunks of K and of V
  const int sr = tid >> 2;
  const int sc0 = (tid & 3) << 4;
  const u16* kbase = qkv + bt0 * 3072 + 1024 + h * 64;
  const u16* vbase = Vt + (size_t)bh * 64 * SEQ;

  bf16x8 kp0 = *(const bf16x8*)(kbase + (size_t)sr * 3072 + sc0);
  bf16x8 kp1 = *(const bf16x8*)(kbase + (size_t)sr * 3072 + sc0 + 8);
  bf16x8 vp0 = *(const bf16x8*)(vbase + (size_t)sr * SEQ + sc0);
  bf16x8 vp1 = *(const bf16x8*)(vbase + (size_t)sr * SEQ + sc0 + 8);

  const int jend = Qb + 128;
  for (int j0 = 0; j0 < jend; j0 += 64) {
    __syncthreads();
    *(bf16x8*)&Ks[sr * 72 + sc0]     = kp0;
    *(bf16x8*)&Ks[sr * 72 + sc0 + 8] = kp1;
    *(bf16x8*)&Vs[sr * 72 + sc0]     = vp0;
    *(bf16x8*)&Vs[sr * 72 + sc0 + 8] = vp1;
    __syncthreads();

    if (j0 + 64 < jend) {                         // T14 prefetch next tile
      const size_t kro = (size_t)(j0 + 64 + sr);
      kp0 = *(const bf16x8*)(kbase + kro * 3072 + sc0);
      kp1 = *(const bf16x8*)(kbase + kro * 3072 + sc0 + 8);
      vp0 = *(const bf16x8*)(vbase + (size_t)sr * SEQ + j0 + 64 + sc0);
      vp1 = *(const bf16x8*)(vbase + (size_t)sr * SEQ + j0 + 64 + sc0 + 8);
    }

    if (j0 > qw + 31) continue;                   // wave fully masked (barriers done)

#pragma unroll
    for (int qt = 0; qt < 2; ++qt) {
      const int qhi = qw + qt * 16 + 15;
      if (j0 > qhi) continue;
      const int nt = min(4, ((qhi - j0) >> 4) + 1);
      const int qrow = qhi - 15 + l15;

      // QK^T swapped: S^T[kv = l4*4+j][q = l15]
      f32x4 s[4];
#pragma unroll
      for (int t = 0; t < 4; ++t) {
        if (t < nt) {
          const bf16x8 ak0 = *(const bf16x8*)&Ks[(t * 16 + l15) * 72 + (l4 << 3)];
          const bf16x8 ak1 = *(const bf16x8*)&Ks[(t * 16 + l15) * 72 + 32 + (l4 << 3)];
          f32x4 a = z4;
          a = __builtin_amdgcn_mfma_f32_16x16x32_bf16(ak0, aq[qt][0], a, 0, 0, 0);
          a = __builtin_amdgcn_mfma_f32_16x16x32_bf16(ak1, aq[qt][1], a, 0, 0, 0);
          s[t] = a;
        }
      }

      float mt = -1e30f;
#pragma unroll
      for (int t = 0; t < 4; ++t) {
        if (t < nt) {
          if (j0 + t * 16 + 15 > qhi - 15) {      // straddling tile: mask (uniform branch)
            const int kvb = j0 + t * 16 + (l4 << 2);
#pragma unroll
            for (int j = 0; j < 4; ++j)
              if (kvb + j > qrow) s[t][j] = -1e30f;
          }
#pragma unroll
          for (int j = 0; j < 4; ++j) mt = fmaxf(mt, s[t][j]);
        }
      }
      mt = fmaxf(mt, __shfl_xor(mt, 16));
      mt = fmaxf(mt, __shfl_xor(mt, 32));
      const float mn = fmaxf(mrun[qt], mt);
      const float mnc = mn * ATT_C;
      const float sc = exp2f(mrun[qt] * ATT_C - mnc);
      mrun[qt] = mn;

      float ls = 0.f;
      uint2 pw[4];
#pragma unroll
      for (int t = 0; t < 4; ++t) {
        if (t < nt) {
          const float p0 = exp2f(__builtin_fmaf(s[t][0], ATT_C, -mnc));
          const float p1 = exp2f(__builtin_fmaf(s[t][1], ATT_C, -mnc));
          const float p2 = exp2f(__builtin_fmaf(s[t][2], ATT_C, -mnc));
          const float p3 = exp2f(__builtin_fmaf(s[t][3], ATT_C, -mnc));
          ls += (p0 + p1) + (p2 + p3);
          pw[t].x = cvtpk(p0, p1);
          pw[t].y = cvtpk(p2, p3);
        } else {
          pw[t].x = 0u; pw[t].y = 0u;
        }
      }
#pragma unroll
      for (int t = 0; t < 4; ++t)
        *(uint2*)&Pw[(qt * 16 + l15) * 72 + t * 16 + (l4 << 2)] = pw[t];

      ls += __shfl_xor(ls, 16);
      ls += __shfl_xor(ls, 32);
      lrun[qt] = lrun[qt] * sc + ls;

#pragma unroll
      for (int dt = 0; dt < 4; ++dt)
#pragma unroll
        for (int j = 0; j < 4; ++j) o[qt][dt][j] *= sc;

      // PV: O^T += mfma(A = V^T[d][kv], B = P^T[kv][q])
      const int nc = (nt + 1) >> 1;
#pragma unroll
      for (int c = 0; c < 2; ++c) {
        if (c < nc) {
          const bf16x8 ap = *(const bf16x8*)&Pw[(qt * 16 + l15) * 72 + c * 32 + (l4 << 3)];
#pragma unroll
          for (int dt = 0; dt < 4; ++dt) {
            const bf16x8 bv = *(const bf16x8*)&Vs[(dt * 16 + l15) * 72 + c * 32 + (l4 << 3)];
            o[qt][dt] = __builtin_amdgcn_mfma_f32_16x16x32_bf16(bv, ap, o[qt][dt], 0, 0, 0);
          }
        }
      }
    }
  }

  // epilogue: normalize, bounce O through Pw ([q][d] bf16), coalesced store
#pragma unroll
  for (int qt = 0; qt < 2; ++qt) {
    const float rl = 1.0f / lrun[qt];
#pragma unroll
    for (int dt = 0; dt < 4; ++dt) {
      uint2 w;
      w.x = cvtpk(o[qt][dt][0] * rl, o[qt][dt][1] * rl);
      w.y = cvtpk(o[qt][dt][2] * rl, o[qt][dt][3] * rl);
      *(uint2*)&Pw[(qt * 16 + l15) * 72 + dt * 16 + (l4 << 2)] = w;
    }
  }
#pragma unroll
  for (int rep = 0; rep < 4; ++rep) {
    const int unit = rep * 64 + lane;             // 32 rows x 8 chunks
    const int r = unit >> 3, c = unit & 7;
    const bf16x8 v = *(const bf16x8*)&Pw[r * 72 + c * 8];
    *(bf16x8*)&attn[(bt0 + qw + r) * EMBED + h * 64 + c * 8] = v;
  }
}

// ---------------- driver ------------------------------------------------------
extern "C" void kernel_launch(void* const* d_in, const int* in_sizes, int n_in,
                              void* d_out, int out_size, void* d_ws, size_t ws_size,
                              hipStream_t stream) {
  const float* x   = (const float*)d_in[0];
  const float* Wq  = (const float*)d_in[1];
  const float* Wk  = (const float*)d_in[2];
  const float* Wv  = (const float*)d_in[3];
  const float* Wo  = (const float*)d_in[4];
  const float* bo  = (const float*)d_in[5];
  const float* W1  = (const float*)d_in[6];
  const float* b1  = (const float*)d_in[7];
  const float* W2  = (const float*)d_in[8];
  const float* b2  = (const float*)d_in[9];
  const float* g1  = (const float*)d_in[10];
  const float* be1 = (const float*)d_in[11];
  const float* g2  = (const float*)d_in[12];
  const float* be2 = (const float*)d_in[13];

  char* ws = (char*)d_ws;
  u16* wqkv_t = (u16*)(ws + 0);                 // [3072][1024] bf16   6 MB
  u16* wo_t   = (u16*)(ws + 6291456);           // [1024][1024]        2 MB
  u16* w1_t   = (u16*)(ws + 8388608);           // [4096][1024]        8 MB
  u16* w2_t   = (u16*)(ws + 16777216);          // [1024][4096]        8 MB
  u16* hbuf   = (u16*)(ws + 25165824);          // LN out, reused     16 MB
  u16* qkv    = (u16*)(ws + 41943040);          // [8192][3072]       48 MB
  u16* ff1    = (u16*)(ws + 41943040);          // overlaps qkv+Vt    64 MB
  u16* vt     = (u16*)(ws + 92274688);          // [64*64][2048]      16 MB
  u16* attnb  = (u16*)(ws + 109051904);         // [8192][1024]       16 MB
  float* x2   = (float*)(ws + 125829120);       // fp32 residual      32 MB
  float* outp = (float*)d_out;

  dim3 blk(256);
  wtrans<<<dim3(32, 32),  blk, 0, stream>>>(Wq, wqkv_t,               1024, 1024);
  wtrans<<<dim3(32, 32),  blk, 0, stream>>>(Wk, wqkv_t + 1024 * 1024, 1024, 1024);
  wtrans<<<dim3(32, 32),  blk, 0, stream>>>(Wv, wqkv_t + 2048 * 1024, 1024, 1024);
  wtrans<<<dim3(32, 32),  blk, 0, stream>>>(Wo, wo_t,                 1024, 1024);
  wtrans<<<dim3(128, 32), blk, 0, stream>>>(W1, w1_t,                 1024, 4096);
  wtrans<<<dim3(32, 128), blk, 0, stream>>>(W2, w2_t,                 4096, 1024);

  ln_kernel<<<dim3(8192), blk, 0, stream>>>(x, g1, be1, hbuf);
  gemm_bt<0><<<dim3(24, 64), blk, 0, stream>>>(hbuf, wqkv_t, qkv, nullptr, nullptr,
                                               8192, 3072, 1024);
  vtrans<<<dim3(64, 128), blk, 0, stream>>>(qkv, vt);
  attn_fwd<<<dim3(16, 64), blk, 0, stream>>>(qkv, vt, attnb);
  gemm_bt<1><<<dim3(8, 64), blk, 0, stream>>>(attnb, wo_t, x2, bo, x,
                                              8192, 1024, 1024);
  ln_kernel<<<dim3(8192), blk, 0, stream>>>(x2, g2, be2, hbuf);
  gemm_bt<2><<<dim3(32, 64), blk, 0, stream>>>(hbuf, w1_t, ff1, b1, nullptr,
                                               8192, 4096, 1024);
  gemm_bt<1><<<dim3(8, 64), blk, 0, stream>>>(ff1, w2_t, outp, b2, x2,
                                              8192, 1024, 4096);
}

// Round 4
// 473.885 us; speedup vs baseline: 1.4419x; 1.1622x over previous
//
#include <hip/hip_runtime.h>

typedef unsigned short u16;
typedef __attribute__((ext_vector_type(8))) short bf16x8;   // 8 bf16 = 4 VGPRs
typedef __attribute__((ext_vector_type(4))) float f32x4;

#define EMBED 1024
#define FFDIM 4096
#define SEQ   2048
#define NTOK  8192
#define ATT_C 0.18033688011112042f   // 0.125 * log2(e)

__device__ __forceinline__ u16 f2bf(float f) {              // RNE fp32->bf16
  union { float f; unsigned int u; } c; c.f = f;
  unsigned int r = ((c.u >> 16) & 1u) + 0x7fffu;
  return (u16)((c.u + r) >> 16);
}

__device__ __forceinline__ unsigned cvtpk(float lo, float hi) {
  unsigned r;
  asm("v_cvt_pk_bf16_f32 %0, %1, %2" : "=v"(r) : "v"(lo), "v"(hi));
  return r;
}

__device__ __forceinline__ void gload16(const u16* g, u16* l) {
  __builtin_amdgcn_global_load_lds((const __attribute__((address_space(1))) void*)g,
                                   (__attribute__((address_space(3))) void*)l, 16, 0, 0);
}

// ---------------- fp32 [K][N] -> bf16 [N][K] (B^T layout for GEMM) -----------
__global__ __launch_bounds__(256) void wtrans(const float* __restrict__ W,
                                              u16* __restrict__ Wt, int K, int N) {
  __shared__ float tile[32][33];
  const int tx = threadIdx.x & 31, ty = threadIdx.x >> 5;
  const int n0 = blockIdx.x << 5, k0 = blockIdx.y << 5;
#pragma unroll
  for (int r = 0; r < 32; r += 8)
    tile[ty + r][tx] = W[(size_t)(k0 + ty + r) * N + n0 + tx];
  __syncthreads();
#pragma unroll
  for (int r = 0; r < 32; r += 8)
    Wt[(size_t)(n0 + ty + r) * K + k0 + tx] = f2bf(tile[tx][ty + r]);
}

// ---------------- V part of qkv [token][2048+h*64+d] -> Vt [bh*64+d][t] ------
__global__ __launch_bounds__(256) void vtrans(const u16* __restrict__ qkv,
                                              u16* __restrict__ Vt) {
  __shared__ u16 tile[32][33];
  const int tx = threadIdx.x & 31, ty = threadIdx.x >> 5;
  const int t0 = blockIdx.x << 5;
  const int rg0 = blockIdx.y << 5;            // global V row = bh*64 + d
  const int bh = rg0 >> 6, d0 = rg0 & 63;
  const int b = bh >> 4, h = bh & 15;
#pragma unroll
  for (int r = 0; r < 32; r += 8)
    tile[ty + r][tx] = qkv[(size_t)(b * SEQ + t0 + ty + r) * 3072 + 2048 + h * 64 + d0 + tx];
  __syncthreads();
#pragma unroll
  for (int r = 0; r < 32; r += 8)
    Vt[(size_t)(rg0 + ty + r) * SEQ + t0 + tx] = tile[tx][ty + r];
}

// ---------------- LayerNorm fp32 in -> bf16 out ------------------------------
__global__ __launch_bounds__(256) void ln_kernel(const float* __restrict__ xin,
                                                 const float* __restrict__ gamma,
                                                 const float* __restrict__ beta,
                                                 u16* __restrict__ out) {
  const int row = blockIdx.x, tid = threadIdx.x;
  const float4 v = reinterpret_cast<const float4*>(xin + (size_t)row * EMBED)[tid];
  float s  = v.x + v.y + v.z + v.w;
  float ss = v.x * v.x + v.y * v.y + v.z * v.z + v.w * v.w;
#pragma unroll
  for (int m = 1; m < 64; m <<= 1) { s += __shfl_xor(s, m); ss += __shfl_xor(ss, m); }
  __shared__ float red[8];
  if ((tid & 63) == 0) { red[tid >> 6] = s; red[4 + (tid >> 6)] = ss; }
  __syncthreads();
  s  = red[0] + red[1] + red[2] + red[3];
  ss = red[4] + red[5] + red[6] + red[7];
  const float mean = s * (1.0f / EMBED);
  const float var  = ss * (1.0f / EMBED) - mean * mean;
  const float rstd = rsqrtf(var + 1e-5f);
  const float4 g  = reinterpret_cast<const float4*>(gamma)[tid];
  const float4 bb = reinterpret_cast<const float4*>(beta)[tid];
  ushort4 o;
  o.x = f2bf((v.x - mean) * rstd * g.x + bb.x);
  o.y = f2bf((v.y - mean) * rstd * g.y + bb.y);
  o.z = f2bf((v.z - mean) * rstd * g.z + bb.z);
  o.w = f2bf((v.w - mean) * rstd * g.w + bb.w);
  reinterpret_cast<ushort4*>(out + (size_t)row * EMBED)[tid] = o;
}

// ---------------- bf16 GEMM, A [M][K] x Bt [N][K] -> C [M][N] ----------------
// EPI 0: store bf16 | 1: +bias +res -> fp32 | 2: +bias, GELU -> bf16
template <int EPI>
__global__ __launch_bounds__(256) void gemm_bt(const u16* __restrict__ A,
                                               const u16* __restrict__ Bt,
                                               void* __restrict__ Cv,
                                               const float* __restrict__ bias,
                                               const float* __restrict__ res,
                                               int M, int N, int K) {
  __shared__ __align__(16) u16 As[128 * 64];   // [row][k], XOR-swizzled
  __shared__ __align__(16) u16 Bs[128 * 64];   // [col][k], XOR-swizzled
  const int tid = threadIdx.x;
  const int lane = tid & 63, wid = tid >> 6;
  const int l4 = lane >> 4, l15 = lane & 15;
  const int wr = wid >> 1, wc = wid & 1;
  const int brow = blockIdx.y << 7, bcol = blockIdx.x << 7;

  const f32x4 z4 = {0.f, 0.f, 0.f, 0.f};
  f32x4 acc[4][4];
#pragma unroll
  for (int m = 0; m < 4; ++m)
#pragma unroll
    for (int n = 0; n < 4; ++n) acc[m][n] = z4;

  const int srow = tid >> 3;
  const int srck = ((tid & 7) << 4) ^ ((srow & 7) << 4);
  const u16* gA = A  + (size_t)(brow + srow) * K + (srck >> 1);
  const u16* gB = Bt + (size_t)(bcol + srow) * K + (srck >> 1);

  const int nk = K >> 6;
  for (int kt = 0; kt < nk; ++kt) {
    __syncthreads();
#pragma unroll
    for (int p = 0; p < 4; ++p) {
      gload16(gA + (size_t)p * 32 * K, &As[(p * 256 + wid * 64) * 8]);
      gload16(gB + (size_t)p * 32 * K, &Bs[(p * 256 + wid * 64) * 8]);
    }
    gA += 64; gB += 64;
    __syncthreads();
#pragma unroll
    for (int ks = 0; ks < 2; ++ks) {
      bf16x8 af[4], bfr[4];
      const int kk = ks * 32 + (l4 << 3);
#pragma unroll
      for (int m = 0; m < 4; ++m) {
        const int r = wr * 64 + m * 16 + l15;
        af[m] = *(const bf16x8*)&As[r * 64 + (kk ^ ((r & 7) << 3))];
      }
#pragma unroll
      for (int n = 0; n < 4; ++n) {
        const int r = wc * 64 + n * 16 + l15;
        bfr[n] = *(const bf16x8*)&Bs[r * 64 + (kk ^ ((r & 7) << 3))];
      }
#pragma unroll
      for (int m = 0; m < 4; ++m)
#pragma unroll
        for (int n = 0; n < 4; ++n)
          acc[m][n] = __builtin_amdgcn_mfma_f32_16x16x32_bf16(af[m], bfr[n], acc[m][n], 0, 0, 0);
    }
  }

  // C/D layout (verified): col = lane&15, row = (lane>>4)*4 + reg
  const int rowb = brow + wr * 64 + (l4 << 2);
  const int colb = bcol + wc * 64 + l15;
#pragma unroll
  for (int n = 0; n < 4; ++n) {
    const int col = colb + n * 16;
    float bv = 0.f;
    if (EPI != 0) bv = bias[col];
#pragma unroll
    for (int m = 0; m < 4; ++m) {
#pragma unroll
      for (int j = 0; j < 4; ++j) {
        const int row = rowb + m * 16 + j;
        const float v = acc[m][n][j];
        if (EPI == 0) {
          ((u16*)Cv)[(size_t)row * N + col] = f2bf(v);
        } else if (EPI == 1) {
          ((float*)Cv)[(size_t)row * N + col] = v + bv + res[(size_t)row * N + col];
        } else {
          const float t = v + bv;
          const float gl = 0.5f * t * (1.0f + erff(t * 0.70710678118654752f));
          ((u16*)Cv)[(size_t)row * N + col] = f2bf(gl);
        }
      }
    }
  }
}

// ---------------- causal flash attention v4 ----------------------------------
// Work-balanced: block p handles q-super-tiles p and 15-p (34 kv-iters each,
// uniform). 4 waves x 32 q-rows, KVBLK=64, swapped QK^T, O^T accumulation,
// exp2 softmax, cvt_pk packing, chunk-skipped PV, T14 reg-prefetch.
__global__ __launch_bounds__(256) void attn_fwd(const u16* __restrict__ qkv,
                                                const u16* __restrict__ Vt,
                                                u16* __restrict__ attn) {
  __shared__ __align__(16) u16 Ks[64 * 72];       // [kv][d], pad 8
  __shared__ __align__(16) u16 Vs[64 * 72];       // [d][kv], pad 8
  __shared__ __align__(16) u16 Ps[4 * 32 * 72];   // per-wave P^T-source [q][kv]
  const int tid = threadIdx.x, lane = tid & 63, wid = tid >> 6;
  const int l4 = lane >> 4, l15 = lane & 15;
  const int bh = blockIdx.y, b = bh >> 4, h = bh & 15;
  const size_t bt0 = (size_t)b * SEQ;
  u16* Pw = &Ps[wid * 32 * 72];

  // staging geometry (invariant): 64 rows x 8 chunks(16B); 2 chunks each of K,V
  const int sr = tid >> 2;
  const int sc0 = (tid & 3) << 4;
  const u16* kbase = qkv + bt0 * 3072 + 1024 + h * 64;
  const u16* vbase = Vt + (size_t)bh * 64 * SEQ;
  const f32x4 z4 = {0.f, 0.f, 0.f, 0.f};

#pragma unroll
  for (int ph = 0; ph < 2; ++ph) {
    const int Qb = ((ph == 0) ? (int)blockIdx.x : 15 - (int)blockIdx.x) << 7;
    const int qw = Qb + wid * 32;                 // wave's first q row

    // Q fragments (B-frag): lane holds Q[q = qw+16qt+l15][d = l4*8.., +32]
    bf16x8 aq[2][2];
#pragma unroll
    for (int qt = 0; qt < 2; ++qt) {
      const u16* qp = qkv + (bt0 + qw + qt * 16 + l15) * 3072 + h * 64 + (l4 << 3);
      aq[qt][0] = *(const bf16x8*)qp;
      aq[qt][1] = *(const bf16x8*)(qp + 32);
    }

    f32x4 o[2][4];                                // O^T: row d, col q=l15
#pragma unroll
    for (int qt = 0; qt < 2; ++qt)
#pragma unroll
      for (int dt = 0; dt < 4; ++dt) o[qt][dt] = z4;
    float mrun[2] = {-1e30f, -1e30f}, lrun[2] = {0.f, 0.f};

    // prologue: preload j0 = 0 for this phase
    bf16x8 kp0 = *(const bf16x8*)(kbase + (size_t)sr * 3072 + sc0);
    bf16x8 kp1 = *(const bf16x8*)(kbase + (size_t)sr * 3072 + sc0 + 8);
    bf16x8 vp0 = *(const bf16x8*)(vbase + (size_t)sr * SEQ + sc0);
    bf16x8 vp1 = *(const bf16x8*)(vbase + (size_t)sr * SEQ + sc0 + 8);

    const int jend = Qb + 128;
    for (int j0 = 0; j0 < jend; j0 += 64) {
      __syncthreads();
      *(bf16x8*)&Ks[sr * 72 + sc0]     = kp0;
      *(bf16x8*)&Ks[sr * 72 + sc0 + 8] = kp1;
      *(bf16x8*)&Vs[sr * 72 + sc0]     = vp0;
      *(bf16x8*)&Vs[sr * 72 + sc0 + 8] = vp1;
      __syncthreads();

      if (j0 + 64 < jend) {                       // T14 prefetch next tile
        const size_t kro = (size_t)(j0 + 64 + sr);
        kp0 = *(const bf16x8*)(kbase + kro * 3072 + sc0);
        kp1 = *(const bf16x8*)(kbase + kro * 3072 + sc0 + 8);
        vp0 = *(const bf16x8*)(vbase + (size_t)sr * SEQ + j0 + 64 + sc0);
        vp1 = *(const bf16x8*)(vbase + (size_t)sr * SEQ + j0 + 64 + sc0 + 8);
      }

      if (j0 > qw + 31) continue;                 // wave fully masked

#pragma unroll
      for (int qt = 0; qt < 2; ++qt) {
        const int qhi = qw + qt * 16 + 15;
        if (j0 > qhi) continue;
        const int nt = min(4, ((qhi - j0) >> 4) + 1);
        const int qrow = qhi - 15 + l15;

        // QK^T swapped: S^T[kv = l4*4+j][q = l15]
        f32x4 s[4];
#pragma unroll
        for (int t = 0; t < 4; ++t) {
          if (t < nt) {
            const bf16x8 ak0 = *(const bf16x8*)&Ks[(t * 16 + l15) * 72 + (l4 << 3)];
            const bf16x8 ak1 = *(const bf16x8*)&Ks[(t * 16 + l15) * 72 + 32 + (l4 << 3)];
            f32x4 a = z4;
            a = __builtin_amdgcn_mfma_f32_16x16x32_bf16(ak0, aq[qt][0], a, 0, 0, 0);
            a = __builtin_amdgcn_mfma_f32_16x16x32_bf16(ak1, aq[qt][1], a, 0, 0, 0);
            s[t] = a;
          }
        }

        float mt = -1e30f;
#pragma unroll
        for (int t = 0; t < 4; ++t) {
          if (t < nt) {
            if (j0 + t * 16 + 15 > qhi - 15) {    // straddling tile: mask
              const int kvb = j0 + t * 16 + (l4 << 2);
#pragma unroll
              for (int j = 0; j < 4; ++j)
                if (kvb + j > qrow) s[t][j] = -1e30f;
            }
#pragma unroll
            for (int j = 0; j < 4; ++j) mt = fmaxf(mt, s[t][j]);
          }
        }
        mt = fmaxf(mt, __shfl_xor(mt, 16));
        mt = fmaxf(mt, __shfl_xor(mt, 32));
        const float mn = fmaxf(mrun[qt], mt);
        const float mnc = mn * ATT_C;
        const float sc = exp2f(mrun[qt] * ATT_C - mnc);
        mrun[qt] = mn;

        float ls = 0.f;
        uint2 pw[4];
#pragma unroll
        for (int t = 0; t < 4; ++t) {
          if (t < nt) {
            const float p0 = exp2f(__builtin_fmaf(s[t][0], ATT_C, -mnc));
            const float p1 = exp2f(__builtin_fmaf(s[t][1], ATT_C, -mnc));
            const float p2 = exp2f(__builtin_fmaf(s[t][2], ATT_C, -mnc));
            const float p3 = exp2f(__builtin_fmaf(s[t][3], ATT_C, -mnc));
            ls += (p0 + p1) + (p2 + p3);
            pw[t].x = cvtpk(p0, p1);
            pw[t].y = cvtpk(p2, p3);
          } else {
            pw[t].x = 0u; pw[t].y = 0u;
          }
        }
#pragma unroll
        for (int t = 0; t < 4; ++t)
          *(uint2*)&Pw[(qt * 16 + l15) * 72 + t * 16 + (l4 << 2)] = pw[t];

        ls += __shfl_xor(ls, 16);
        ls += __shfl_xor(ls, 32);
        lrun[qt] = lrun[qt] * sc + ls;

#pragma unroll
        for (int dt = 0; dt < 4; ++dt)
#pragma unroll
          for (int j = 0; j < 4; ++j) o[qt][dt][j] *= sc;

        // PV: O^T += mfma(A = V^T[d][kv], B = P^T[kv][q])
        const int nc = (nt + 1) >> 1;
#pragma unroll
        for (int c = 0; c < 2; ++c) {
          if (c < nc) {
            const bf16x8 ap = *(const bf16x8*)&Pw[(qt * 16 + l15) * 72 + c * 32 + (l4 << 3)];
#pragma unroll
            for (int dt = 0; dt < 4; ++dt) {
              const bf16x8 bv = *(const bf16x8*)&Vs[(dt * 16 + l15) * 72 + c * 32 + (l4 << 3)];
              o[qt][dt] = __builtin_amdgcn_mfma_f32_16x16x32_bf16(bv, ap, o[qt][dt], 0, 0, 0);
            }
          }
        }
      }
    }

    // epilogue: normalize, bounce O through Pw ([q][d] bf16), coalesced store
#pragma unroll
    for (int qt = 0; qt < 2; ++qt) {
      const float rl = 1.0f / lrun[qt];
#pragma unroll
      for (int dt = 0; dt < 4; ++dt) {
        uint2 w;
        w.x = cvtpk(o[qt][dt][0] * rl, o[qt][dt][1] * rl);
        w.y = cvtpk(o[qt][dt][2] * rl, o[qt][dt][3] * rl);
        *(uint2*)&Pw[(qt * 16 + l15) * 72 + dt * 16 + (l4 << 2)] = w;
      }
    }
#pragma unroll
    for (int rep = 0; rep < 4; ++rep) {
      const int unit = rep * 64 + lane;           // 32 rows x 8 chunks
      const int r = unit >> 3, c = unit & 7;
      const bf16x8 v = *(const bf16x8*)&Pw[r * 72 + c * 8];
      *(bf16x8*)&attn[(bt0 + qw + r) * EMBED + h * 64 + c * 8] = v;
    }
  }
}

// ---------------- driver ------------------------------------------------------
extern "C" void kernel_launch(void* const* d_in, const int* in_sizes, int n_in,
                              void* d_out, int out_size, void* d_ws, size_t ws_size,
                              hipStream_t stream) {
  const float* x   = (const float*)d_in[0];
  const float* Wq  = (const float*)d_in[1];
  const float* Wk  = (const float*)d_in[2];
  const float* Wv  = (const float*)d_in[3];
  const float* Wo  = (const float*)d_in[4];
  const float* bo  = (const float*)d_in[5];
  const float* W1  = (const float*)d_in[6];
  const float* b1  = (const float*)d_in[7];
  const float* W2  = (const float*)d_in[8];
  const float* b2  = (const float*)d_in[9];
  const float* g1  = (const float*)d_in[10];
  const float* be1 = (const float*)d_in[11];
  const float* g2  = (const float*)d_in[12];
  const float* be2 = (const float*)d_in[13];

  char* ws = (char*)d_ws;
  u16* wqkv_t = (u16*)(ws + 0);                 // [3072][1024] bf16   6 MB
  u16* wo_t   = (u16*)(ws + 6291456);           // [1024][1024]        2 MB
  u16* w1_t   = (u16*)(ws + 8388608);           // [4096][1024]        8 MB
  u16* w2_t   = (u16*)(ws + 16777216);          // [1024][4096]        8 MB
  u16* hbuf   = (u16*)(ws + 25165824);          // LN out, reused     16 MB
  u16* qkv    = (u16*)(ws + 41943040);          // [8192][3072]       48 MB
  u16* ff1    = (u16*)(ws + 41943040);          // overlaps qkv+Vt    64 MB
  u16* vt     = (u16*)(ws + 92274688);          // [64*64][2048]      16 MB
  u16* attnb  = (u16*)(ws + 109051904);         // [8192][1024]       16 MB
  float* x2   = (float*)(ws + 125829120);       // fp32 residual      32 MB
  float* outp = (float*)d_out;

  dim3 blk(256);
  wtrans<<<dim3(32, 32),  blk, 0, stream>>>(Wq, wqkv_t,               1024, 1024);
  wtrans<<<dim3(32, 32),  blk, 0, stream>>>(Wk, wqkv_t + 1024 * 1024, 1024, 1024);
  wtrans<<<dim3(32, 32),  blk, 0, stream>>>(Wv, wqkv_t + 2048 * 1024, 1024, 1024);
  wtrans<<<dim3(32, 32),  blk, 0, stream>>>(Wo, wo_t,                 1024, 1024);
  wtrans<<<dim3(128, 32), blk, 0, stream>>>(W1, w1_t,                 1024, 4096);
  wtrans<<<dim3(32, 128), blk, 0, stream>>>(W2, w2_t,                 4096, 1024);

  ln_kernel<<<dim3(8192), blk, 0, stream>>>(x, g1, be1, hbuf);
  gemm_bt<0><<<dim3(24, 64), blk, 0, stream>>>(hbuf, wqkv_t, qkv, nullptr, nullptr,
                                               8192, 3072, 1024);
  vtrans<<<dim3(64, 128), blk, 0, stream>>>(qkv, vt);
  attn_fwd<<<dim3(8, 64), blk, 0, stream>>>(qkv, vt, attnb);
  gemm_bt<1><<<dim3(8, 64), blk, 0, stream>>>(attnb, wo_t, x2, bo, x,
                                              8192, 1024, 1024);
  ln_kernel<<<dim3(8192), blk, 0, stream>>>(x2, g2, be2, hbuf);
  gemm_bt<2><<<dim3(32, 64), blk, 0, stream>>>(hbuf, w1_t, ff1, b1, nullptr,
                                               8192, 4096, 1024);
  gemm_bt<1><<<dim3(8, 64), blk, 0, stream>>>(ff1, w2_t, outp, b2, x2,
                                              8192, 1024, 4096);
}

// Round 6
// 432.000 us; speedup vs baseline: 1.5817x; 1.0970x over previous
//
#include <hip/hip_runtime.h>

typedef unsigned short u16;
typedef __attribute__((ext_vector_type(8))) short bf16x8;   // 8 bf16 = 4 VGPRs
typedef __attribute__((ext_vector_type(4))) float f32x4;

#define EMBED 1024
#define FFDIM 4096
#define SEQ   2048
#define NTOK  8192
#define ATT_C 0.18033688011112042f   // 0.125 * log2(e)

__device__ __forceinline__ u16 f2bf(float f) {              // RNE fp32->bf16
  union { float f; unsigned int u; } c; c.f = f;
  unsigned int r = ((c.u >> 16) & 1u) + 0x7fffu;
  return (u16)((c.u + r) >> 16);
}

__device__ __forceinline__ unsigned cvtpk(float lo, float hi) {
  unsigned r;
  asm("v_cvt_pk_bf16_f32 %0, %1, %2" : "=v"(r) : "v"(lo), "v"(hi));
  return r;
}

__device__ __forceinline__ void gload16(const u16* g, u16* l) {
  __builtin_amdgcn_global_load_lds((const __attribute__((address_space(1))) void*)g,
                                   (__attribute__((address_space(3))) void*)l, 16, 0, 0);
}

// ---------------- fp32 [K][N] -> bf16 [N][K] (B^T layout for GEMM) -----------
__global__ __launch_bounds__(256) void wtrans(const float* __restrict__ W,
                                              u16* __restrict__ Wt, int K, int N) {
  __shared__ float tile[32][33];
  const int tx = threadIdx.x & 31, ty = threadIdx.x >> 5;
  const int n0 = blockIdx.x << 5, k0 = blockIdx.y << 5;
#pragma unroll
  for (int r = 0; r < 32; r += 8)
    tile[ty + r][tx] = W[(size_t)(k0 + ty + r) * N + n0 + tx];
  __syncthreads();
#pragma unroll
  for (int r = 0; r < 32; r += 8)
    Wt[(size_t)(n0 + ty + r) * K + k0 + tx] = f2bf(tile[tx][ty + r]);
}

// ---------------- V part of qkv [token][2048+h*64+d] -> Vt [bh*64+d][t] ------
__global__ __launch_bounds__(256) void vtrans(const u16* __restrict__ qkv,
                                              u16* __restrict__ Vt) {
  __shared__ u16 tile[32][33];
  const int tx = threadIdx.x & 31, ty = threadIdx.x >> 5;
  const int t0 = blockIdx.x << 5;
  const int rg0 = blockIdx.y << 5;            // global V row = bh*64 + d
  const int bh = rg0 >> 6, d0 = rg0 & 63;
  const int b = bh >> 4, h = bh & 15;
#pragma unroll
  for (int r = 0; r < 32; r += 8)
    tile[ty + r][tx] = qkv[(size_t)(b * SEQ + t0 + ty + r) * 3072 + 2048 + h * 64 + d0 + tx];
  __syncthreads();
#pragma unroll
  for (int r = 0; r < 32; r += 8)
    Vt[(size_t)(rg0 + ty + r) * SEQ + t0 + tx] = tile[tx][ty + r];
}

// ---------------- LayerNorm fp32 in -> bf16 out ------------------------------
__global__ __launch_bounds__(256) void ln_kernel(const float* __restrict__ xin,
                                                 const float* __restrict__ gamma,
                                                 const float* __restrict__ beta,
                                                 u16* __restrict__ out) {
  const int row = blockIdx.x, tid = threadIdx.x;
  const float4 v = reinterpret_cast<const float4*>(xin + (size_t)row * EMBED)[tid];
  float s  = v.x + v.y + v.z + v.w;
  float ss = v.x * v.x + v.y * v.y + v.z * v.z + v.w * v.w;
#pragma unroll
  for (int m = 1; m < 64; m <<= 1) { s += __shfl_xor(s, m); ss += __shfl_xor(ss, m); }
  __shared__ float red[8];
  if ((tid & 63) == 0) { red[tid >> 6] = s; red[4 + (tid >> 6)] = ss; }
  __syncthreads();
  s  = red[0] + red[1] + red[2] + red[3];
  ss = red[4] + red[5] + red[6] + red[7];
  const float mean = s * (1.0f / EMBED);
  const float var  = ss * (1.0f / EMBED) - mean * mean;
  const float rstd = rsqrtf(var + 1e-5f);
  const float4 g  = reinterpret_cast<const float4*>(gamma)[tid];
  const float4 bb = reinterpret_cast<const float4*>(beta)[tid];
  ushort4 o;
  o.x = f2bf((v.x - mean) * rstd * g.x + bb.x);
  o.y = f2bf((v.y - mean) * rstd * g.y + bb.y);
  o.z = f2bf((v.z - mean) * rstd * g.z + bb.z);
  o.w = f2bf((v.w - mean) * rstd * g.w + bb.w);
  reinterpret_cast<ushort4*>(out + (size_t)row * EMBED)[tid] = o;
}

// ---------------- bf16 GEMM, A [M][K] x Bt [N][K] -> C [M][N] ----------------
// EPI 0: store bf16 | 1: +bias +res -> fp32 | 2: +bias, GELU -> bf16
// T1: bijective XCD swizzle (requires total blocks % 8 == 0 -- all call sites ok)
template <int EPI>
__global__ __launch_bounds__(256) void gemm_bt(const u16* __restrict__ A,
                                               const u16* __restrict__ Bt,
                                               void* __restrict__ Cv,
                                               const float* __restrict__ bias,
                                               const float* __restrict__ res,
                                               int M, int N, int K) {
  __shared__ __align__(16) u16 As[128 * 64];   // [row][k], XOR-swizzled
  __shared__ __align__(16) u16 Bs[128 * 64];   // [col][k], XOR-swizzled
  const int tid = threadIdx.x;
  const int lane = tid & 63, wid = tid >> 6;
  const int l4 = lane >> 4, l15 = lane & 15;
  const int wr = wid >> 1, wc = wid & 1;

  const int gx = gridDim.x;
  const int nwg = gx * gridDim.y;
  const int flat = (int)blockIdx.y * gx + (int)blockIdx.x;
  const int cpx = nwg >> 3;                    // blocks per XCD chunk
  const int swz = (flat & 7) * cpx + (flat >> 3);
  const int brow = (swz / gx) << 7, bcol = (swz % gx) << 7;

  const f32x4 z4 = {0.f, 0.f, 0.f, 0.f};
  f32x4 acc[4][4];
#pragma unroll
  for (int m = 0; m < 4; ++m)
#pragma unroll
    for (int n = 0; n < 4; ++n) acc[m][n] = z4;

  const int srow = tid >> 3;
  const int srck = ((tid & 7) << 4) ^ ((srow & 7) << 4);
  const u16* gA = A  + (size_t)(brow + srow) * K + (srck >> 1);
  const u16* gB = Bt + (size_t)(bcol + srow) * K + (srck >> 1);

  const int nk = K >> 6;
  for (int kt = 0; kt < nk; ++kt) {
    __syncthreads();
#pragma unroll
    for (int p = 0; p < 4; ++p) {
      gload16(gA + (size_t)p * 32 * K, &As[(p * 256 + wid * 64) * 8]);
      gload16(gB + (size_t)p * 32 * K, &Bs[(p * 256 + wid * 64) * 8]);
    }
    gA += 64; gB += 64;
    __syncthreads();
#pragma unroll
    for (int ks = 0; ks < 2; ++ks) {
      bf16x8 af[4], bfr[4];
      const int kk = ks * 32 + (l4 << 3);
#pragma unroll
      for (int m = 0; m < 4; ++m) {
        const int r = wr * 64 + m * 16 + l15;
        af[m] = *(const bf16x8*)&As[r * 64 + (kk ^ ((r & 7) << 3))];
      }
#pragma unroll
      for (int n = 0; n < 4; ++n) {
        const int r = wc * 64 + n * 16 + l15;
        bfr[n] = *(const bf16x8*)&Bs[r * 64 + (kk ^ ((r & 7) << 3))];
      }
#pragma unroll
      for (int m = 0; m < 4; ++m)
#pragma unroll
        for (int n = 0; n < 4; ++n)
          acc[m][n] = __builtin_amdgcn_mfma_f32_16x16x32_bf16(af[m], bfr[n], acc[m][n], 0, 0, 0);
    }
  }

  // C/D layout (verified): col = lane&15, row = (lane>>4)*4 + reg
  const int rowb = brow + wr * 64 + (l4 << 2);
  const int colb = bcol + wc * 64 + l15;
#pragma unroll
  for (int n = 0; n < 4; ++n) {
    const int col = colb + n * 16;
    float bv = 0.f;
    if (EPI != 0) bv = bias[col];
#pragma unroll
    for (int m = 0; m < 4; ++m) {
#pragma unroll
      for (int j = 0; j < 4; ++j) {
        const int row = rowb + m * 16 + j;
        const float v = acc[m][n][j];
        if (EPI == 0) {
          ((u16*)Cv)[(size_t)row * N + col] = f2bf(v);
        } else if (EPI == 1) {
          ((float*)Cv)[(size_t)row * N + col] = v + bv + res[(size_t)row * N + col];
        } else {
          const float t = v + bv;
          const float gl = 0.5f * t * (1.0f + erff(t * 0.70710678118654752f));
          ((u16*)Cv)[(size_t)row * N + col] = f2bf(gl);
        }
      }
    }
  }
}

// ---------------- causal flash attention v5b ---------------------------------
// 8 waves x 16 q-rows (512 thr, 128 q/block), balanced pairing p & 15-p.
// Swapped QK^T, O^T accumulation, exp2 softmax, T13 defer-rescale, cvt_pk,
// chunk-skipped PV, T14 reg-prefetch, LDS-bounced coalesced output.
// FIX vs v5: staging column step is (tid&7)<<3 (one 8-u16 chunk per thread).
__global__ __launch_bounds__(512) void attn_fwd(const u16* __restrict__ qkv,
                                                const u16* __restrict__ Vt,
                                                u16* __restrict__ attn) {
  __shared__ __align__(16) u16 Ks[64 * 72];       // [kv][d], pad 8
  __shared__ __align__(16) u16 Vs[64 * 72];       // [d][kv], pad 8
  __shared__ __align__(16) u16 Ps[8 * 16 * 72];   // per-wave P^T-source [q][kv]
  const int tid = threadIdx.x, lane = tid & 63, wid = tid >> 6;
  const int l4 = lane >> 4, l15 = lane & 15;
  const int bh = blockIdx.y, b = bh >> 4, h = bh & 15;
  const size_t bt0 = (size_t)b * SEQ;
  u16* Pw = &Ps[wid * 16 * 72];

  // staging: 64 rows x 8 chunks(16B) each of K and V; 512 thr -> 1 chunk each
  const int sr = tid >> 3;
  const int sc0 = (tid & 7) << 3;                 // u16 col: 0,8,...,56
  const u16* kbase = qkv + bt0 * 3072 + 1024 + h * 64;
  const u16* vbase = Vt + (size_t)bh * 64 * SEQ;
  const f32x4 z4 = {0.f, 0.f, 0.f, 0.f};

#pragma unroll
  for (int ph = 0; ph < 2; ++ph) {
    const int Qb = ((ph == 0) ? (int)blockIdx.x : 15 - (int)blockIdx.x) << 7;
    const int qw = Qb + wid * 16;                 // wave's first q row
    const int qlane = qw + l15;

    // Q fragment (B-frag): lane holds Q[q = qw+l15][d = l4*8.., +32]
    const u16* qp = qkv + (bt0 + qlane) * 3072 + h * 64 + (l4 << 3);
    const bf16x8 aq0 = *(const bf16x8*)qp;
    const bf16x8 aq1 = *(const bf16x8*)(qp + 32);

    f32x4 o[4];                                   // O^T: row d=dt*16+l4*4+j, col q=l15
#pragma unroll
    for (int dt = 0; dt < 4; ++dt) o[dt] = z4;
    float mrun = -1e30f, lrun = 0.f;

    // prologue: preload j0 = 0 for this phase
    bf16x8 kp = *(const bf16x8*)(kbase + (size_t)sr * 3072 + sc0);
    bf16x8 vp = *(const bf16x8*)(vbase + (size_t)sr * SEQ + sc0);

    const int jend = Qb + 128;
    for (int j0 = 0; j0 < jend; j0 += 64) {
      __syncthreads();
      *(bf16x8*)&Ks[sr * 72 + sc0] = kp;
      *(bf16x8*)&Vs[sr * 72 + sc0] = vp;
      __syncthreads();

      if (j0 + 64 < jend) {                       // T14 prefetch next tile
        kp = *(const bf16x8*)(kbase + (size_t)(j0 + 64 + sr) * 3072 + sc0);
        vp = *(const bf16x8*)(vbase + (size_t)sr * SEQ + j0 + 64 + sc0);
      }

      if (j0 > qw + 15) continue;                 // wave fully masked
      const int nt = min(4, ((qw + 15 - j0) >> 4) + 1);

      // QK^T swapped: S^T[kv = t*16 + l4*4+j][q = l15]
      f32x4 s[4];
#pragma unroll
      for (int t = 0; t < 4; ++t) {
        if (t < nt) {
          const bf16x8 ak0 = *(const bf16x8*)&Ks[(t * 16 + l15) * 72 + (l4 << 3)];
          const bf16x8 ak1 = *(const bf16x8*)&Ks[(t * 16 + l15) * 72 + 32 + (l4 << 3)];
          f32x4 a = z4;
          a = __builtin_amdgcn_mfma_f32_16x16x32_bf16(ak0, aq0, a, 0, 0, 0);
          a = __builtin_amdgcn_mfma_f32_16x16x32_bf16(ak1, aq1, a, 0, 0, 0);
          s[t] = a;
        }
      }

      float mt = -1e30f;
#pragma unroll
      for (int t = 0; t < 4; ++t) {
        if (t < nt) {
          if (j0 + t * 16 + 15 > qw) {            // straddling tile: mask
            const int kvb = j0 + t * 16 + (l4 << 2);
#pragma unroll
            for (int j = 0; j < 4; ++j)
              if (kvb + j > qlane) s[t][j] = -1e30f;
          }
          mt = fmaxf(mt, fmaxf(fmaxf(s[t][0], s[t][1]), fmaxf(s[t][2], s[t][3])));
        }
      }
      mt = fmaxf(mt, __shfl_xor(mt, 16));
      mt = fmaxf(mt, __shfl_xor(mt, 32));

      // T13 defer-rescale: skip when new max within threshold (exp2 arg <= 8)
      const bool skip = __all(mt <= mrun + 44.0f);
      float scq = 1.0f;
      if (!skip) {
        const float mn = fmaxf(mrun, mt);
        scq = exp2f((mrun - mn) * ATT_C);
        mrun = mn;
      }
      const float mc = mrun * ATT_C;

      float ls = 0.f;
      uint2 pw[4];
#pragma unroll
      for (int t = 0; t < 4; ++t) {
        if (t < nt) {
          const float p0 = exp2f(__builtin_fmaf(s[t][0], ATT_C, -mc));
          const float p1 = exp2f(__builtin_fmaf(s[t][1], ATT_C, -mc));
          const float p2 = exp2f(__builtin_fmaf(s[t][2], ATT_C, -mc));
          const float p3 = exp2f(__builtin_fmaf(s[t][3], ATT_C, -mc));
          ls += (p0 + p1) + (p2 + p3);
          pw[t].x = cvtpk(p0, p1);
          pw[t].y = cvtpk(p2, p3);
        } else {
          pw[t].x = 0u; pw[t].y = 0u;
        }
      }
#pragma unroll
      for (int t = 0; t < 4; ++t)
        *(uint2*)&Pw[l15 * 72 + t * 16 + (l4 << 2)] = pw[t];

      ls += __shfl_xor(ls, 16);
      ls += __shfl_xor(ls, 32);

      if (!skip) {
        lrun = lrun * scq + ls;
#pragma unroll
        for (int dt = 0; dt < 4; ++dt)
#pragma unroll
          for (int j = 0; j < 4; ++j) o[dt][j] *= scq;
      } else {
        lrun += ls;
      }

      // PV: O^T += mfma(A = V^T[d][kv], B = P^T[kv][q])
      const int nc = (nt + 1) >> 1;
#pragma unroll
      for (int c = 0; c < 2; ++c) {
        if (c < nc) {
          const bf16x8 ap = *(const bf16x8*)&Pw[l15 * 72 + c * 32 + (l4 << 3)];
#pragma unroll
          for (int dt = 0; dt < 4; ++dt) {
            const bf16x8 bv = *(const bf16x8*)&Vs[(dt * 16 + l15) * 72 + c * 32 + (l4 << 3)];
            o[dt] = __builtin_amdgcn_mfma_f32_16x16x32_bf16(bv, ap, o[dt], 0, 0, 0);
          }
        }
      }
    }

    // epilogue: normalize, bounce O through Pw ([q][d] bf16), coalesced store
    const float rl = 1.0f / lrun;
#pragma unroll
    for (int dt = 0; dt < 4; ++dt) {
      uint2 w;
      w.x = cvtpk(o[dt][0] * rl, o[dt][1] * rl);
      w.y = cvtpk(o[dt][2] * rl, o[dt][3] * rl);
      *(uint2*)&Pw[l15 * 72 + dt * 16 + (l4 << 2)] = w;
    }
#pragma unroll
    for (int rep = 0; rep < 2; ++rep) {
      const int unit = rep * 64 + lane;           // 16 rows x 8 chunks
      const int r = unit >> 3, c = unit & 7;
      const bf16x8 v = *(const bf16x8*)&Pw[r * 72 + c * 8];
      *(bf16x8*)&attn[(bt0 + qw + r) * EMBED + h * 64 + c * 8] = v;
    }
  }
}

// ---------------- driver ------------------------------------------------------
extern "C" void kernel_launch(void* const* d_in, const int* in_sizes, int n_in,
                              void* d_out, int out_size, void* d_ws, size_t ws_size,
                              hipStream_t stream) {
  const float* x   = (const float*)d_in[0];
  const float* Wq  = (const float*)d_in[1];
  const float* Wk  = (const float*)d_in[2];
  const float* Wv  = (const float*)d_in[3];
  const float* Wo  = (const float*)d_in[4];
  const float* bo  = (const float*)d_in[5];
  const float* W1  = (const float*)d_in[6];
  const float* b1  = (const float*)d_in[7];
  const float* W2  = (const float*)d_in[8];
  const float* b2  = (const float*)d_in[9];
  const float* g1  = (const float*)d_in[10];
  const float* be1 = (const float*)d_in[11];
  const float* g2  = (const float*)d_in[12];
  const float* be2 = (const float*)d_in[13];

  char* ws = (char*)d_ws;
  u16* wqkv_t = (u16*)(ws + 0);                 // [3072][1024] bf16   6 MB
  u16* wo_t   = (u16*)(ws + 6291456);           // [1024][1024]        2 MB
  u16* w1_t   = (u16*)(ws + 8388608);           // [4096][1024]        8 MB
  u16* w2_t   = (u16*)(ws + 16777216);          // [1024][4096]        8 MB
  u16* hbuf   = (u16*)(ws + 25165824);          // LN out, reused     16 MB
  u16* qkv    = (u16*)(ws + 41943040);          // [8192][3072]       48 MB
  u16* ff1    = (u16*)(ws + 41943040);          // overlaps qkv+Vt    64 MB
  u16* vt     = (u16*)(ws + 92274688);          // [64*64][2048]      16 MB
  u16* attnb  = (u16*)(ws + 109051904);         // [8192][1024]       16 MB
  float* x2   = (float*)(ws + 125829120);       // fp32 residual      32 MB
  float* outp = (float*)d_out;

  dim3 blk(256);
  wtrans<<<dim3(32, 32),  blk, 0, stream>>>(Wq, wqkv_t,               1024, 1024);
  wtrans<<<dim3(32, 32),  blk, 0, stream>>>(Wk, wqkv_t + 1024 * 1024, 1024, 1024);
  wtrans<<<dim3(32, 32),  blk, 0, stream>>>(Wv, wqkv_t + 2048 * 1024, 1024, 1024);
  wtrans<<<dim3(32, 32),  blk, 0, stream>>>(Wo, wo_t,                 1024, 1024);
  wtrans<<<dim3(128, 32), blk, 0, stream>>>(W1, w1_t,                 1024, 4096);
  wtrans<<<dim3(32, 128), blk, 0, stream>>>(W2, w2_t,                 4096, 1024);

  ln_kernel<<<dim3(8192), blk, 0, stream>>>(x, g1, be1, hbuf);
  gemm_bt<0><<<dim3(24, 64), blk, 0, stream>>>(hbuf, wqkv_t, qkv, nullptr, nullptr,
                                               8192, 3072, 1024);
  vtrans<<<dim3(64, 128), blk, 0, stream>>>(qkv, vt);
  attn_fwd<<<dim3(8, 64), dim3(512), 0, stream>>>(qkv, vt, attnb);
  gemm_bt<1><<<dim3(8, 64), blk, 0, stream>>>(attnb, wo_t, x2, bo, x,
                                              8192, 1024, 1024);
  ln_kernel<<<dim3(8192), blk, 0, stream>>>(x2, g2, be2, hbuf);
  gemm_bt<2><<<dim3(32, 64), blk, 0, stream>>>(hbuf, w1_t, ff1, b1, nullptr,
                                               8192, 4096, 1024);
  gemm_bt<1><<<dim3(8, 64), blk, 0, stream>>>(ff1, w2_t, outp, b2, x2,
                                              8192, 1024, 4096);
}

// Round 7
// 418.177 us; speedup vs baseline: 1.6340x; 1.0331x over previous
//
#include <hip/hip_runtime.h>

typedef unsigned short u16;
typedef __attribute__((ext_vector_type(8))) short bf16x8;   // 8 bf16 = 4 VGPRs
typedef __attribute__((ext_vector_type(4))) float f32x4;

#define EMBED 1024
#define FFDIM 4096
#define SEQ   2048
#define NTOK  8192
#define ATT_C 0.18033688011112042f   // 0.125 * log2(e)

__device__ __forceinline__ u16 f2bf(float f) {              // RNE fp32->bf16
  union { float f; unsigned int u; } c; c.f = f;
  unsigned int r = ((c.u >> 16) & 1u) + 0x7fffu;
  return (u16)((c.u + r) >> 16);
}

__device__ __forceinline__ unsigned cvtpk(float lo, float hi) {
  unsigned r;
  asm("v_cvt_pk_bf16_f32 %0, %1, %2" : "=v"(r) : "v"(lo), "v"(hi));
  return r;
}

__device__ __forceinline__ void gload16(const u16* g, u16* l) {
  __builtin_amdgcn_global_load_lds((const __attribute__((address_space(1))) void*)g,
                                   (__attribute__((address_space(3))) void*)l, 16, 0, 0);
}

// ---------------- fp32 [K][N] -> bf16 [N][K] (B^T layout for GEMM) -----------
__global__ __launch_bounds__(256) void wtrans(const float* __restrict__ W,
                                              u16* __restrict__ Wt, int K, int N) {
  __shared__ float tile[32][33];
  const int tx = threadIdx.x & 31, ty = threadIdx.x >> 5;
  const int n0 = blockIdx.x << 5, k0 = blockIdx.y << 5;
#pragma unroll
  for (int r = 0; r < 32; r += 8)
    tile[ty + r][tx] = W[(size_t)(k0 + ty + r) * N + n0 + tx];
  __syncthreads();
#pragma unroll
  for (int r = 0; r < 32; r += 8)
    Wt[(size_t)(n0 + ty + r) * K + k0 + tx] = f2bf(tile[tx][ty + r]);
}

// ---------------- V part of qkv [token][2048+h*64+d] -> Vt [bh*64+d][t] ------
__global__ __launch_bounds__(256) void vtrans(const u16* __restrict__ qkv,
                                              u16* __restrict__ Vt) {
  __shared__ u16 tile[32][33];
  const int tx = threadIdx.x & 31, ty = threadIdx.x >> 5;
  const int t0 = blockIdx.x << 5;
  const int rg0 = blockIdx.y << 5;            // global V row = bh*64 + d
  const int bh = rg0 >> 6, d0 = rg0 & 63;
  const int b = bh >> 4, h = bh & 15;
#pragma unroll
  for (int r = 0; r < 32; r += 8)
    tile[ty + r][tx] = qkv[(size_t)(b * SEQ + t0 + ty + r) * 3072 + 2048 + h * 64 + d0 + tx];
  __syncthreads();
#pragma unroll
  for (int r = 0; r < 32; r += 8)
    Vt[(size_t)(rg0 + ty + r) * SEQ + t0 + tx] = tile[tx][ty + r];
}

// ---------------- LayerNorm fp32 in -> bf16 out ------------------------------
__global__ __launch_bounds__(256) void ln_kernel(const float* __restrict__ xin,
                                                 const float* __restrict__ gamma,
                                                 const float* __restrict__ beta,
                                                 u16* __restrict__ out) {
  const int row = blockIdx.x, tid = threadIdx.x;
  const float4 v = reinterpret_cast<const float4*>(xin + (size_t)row * EMBED)[tid];
  float s  = v.x + v.y + v.z + v.w;
  float ss = v.x * v.x + v.y * v.y + v.z * v.z + v.w * v.w;
#pragma unroll
  for (int m = 1; m < 64; m <<= 1) { s += __shfl_xor(s, m); ss += __shfl_xor(ss, m); }
  __shared__ float red[8];
  if ((tid & 63) == 0) { red[tid >> 6] = s; red[4 + (tid >> 6)] = ss; }
  __syncthreads();
  s  = red[0] + red[1] + red[2] + red[3];
  ss = red[4] + red[5] + red[6] + red[7];
  const float mean = s * (1.0f / EMBED);
  const float var  = ss * (1.0f / EMBED) - mean * mean;
  const float rstd = rsqrtf(var + 1e-5f);
  const float4 g  = reinterpret_cast<const float4*>(gamma)[tid];
  const float4 bb = reinterpret_cast<const float4*>(beta)[tid];
  ushort4 o;
  o.x = f2bf((v.x - mean) * rstd * g.x + bb.x);
  o.y = f2bf((v.y - mean) * rstd * g.y + bb.y);
  o.z = f2bf((v.z - mean) * rstd * g.z + bb.z);
  o.w = f2bf((v.w - mean) * rstd * g.w + bb.w);
  reinterpret_cast<ushort4*>(out + (size_t)row * EMBED)[tid] = o;
}

// ---------------- bf16 GEMM v2: 256xBN tile, counted-vmcnt pipeline ----------
// 8 waves (512 thr), wave (wm,wn) = (wid>>2, wid&3) owns 128 x (BN/4) output.
// BK=64, 2 LDS buffers, XOR-swizzled rows (conflict-free, verified R6).
// Protocol per K-tile t (buf c = t&1):
//   [tile t landed, barrier]  ds_read ks0 -> 32*NREP/4 MFMA (setprio)
//   ds_read ks1 -> lgkmcnt(0) -> barrier (all reads of buf c done)
//   issue STAGE(buf c <- tile t+2)  (flies ~2 K-tiles)
//   MFMA ks1 (setprio) -> vmcnt(TLOADS) (tile t+1 landed, t+2 in flight) -> barrier
// EPI 0: bf16 | 1: +bias +res -> fp32 | 2: +bias GELU -> bf16
template <int NREP, int EPI>
__global__ __launch_bounds__(512, 2) void gemm2(const u16* __restrict__ A,
                                                const u16* __restrict__ Bt,
                                                void* __restrict__ Cv,
                                                const float* __restrict__ bias,
                                                const float* __restrict__ res,
                                                int M, int N, int K) {
  constexpr int BN = NREP * 64;
  constexpr int TLOADS = 4 + NREP;                 // gload_lds per thread per tile
  __shared__ __align__(16) u16 As[2][256 * 64];    // [row][k] swizzled
  __shared__ __align__(16) u16 Bs[2][BN * 64];     // [col][k] swizzled

  const int tid = threadIdx.x;
  const int lane = tid & 63, wid = tid >> 6;
  const int l4 = lane >> 4, l15 = lane & 15;
  const int wm = wid >> 2, wn = wid & 3;

  const int gx = gridDim.x;
  const int nwg = gx * (int)gridDim.y;
  const int flat = (int)blockIdx.y * gx + (int)blockIdx.x;
  const int cpx = nwg >> 3;                        // bijective XCD swizzle (nwg%8==0)
  const int swz = (flat & 7) * cpx + (flat >> 3);
  const int brow = (swz / gx) << 8;
  const int bcol = (swz % gx) * BN;

  const f32x4 z4 = {0.f, 0.f, 0.f, 0.f};
  f32x4 acc[8][NREP];
#pragma unroll
  for (int m = 0; m < 8; ++m)
#pragma unroll
    for (int n = 0; n < NREP; ++n) acc[m][n] = z4;

  // staging: thread -> LDS slot (tid + k*512), row = slot>>3, 16B chunk slot&7;
  // source column pre-XOR'd so linear LDS + swizzled read = consistent involution
  const int srow = tid >> 3;
  const int scolb = ((tid & 7) << 4) ^ ((srow & 7) << 4);
  const u16* gA = A  + (size_t)(brow + srow) * K + (scolb >> 1);
  const u16* gB = Bt + (size_t)(bcol + srow) * K + (scolb >> 1);
  const int lbase = wid * 64 * 8;                  // wave-uniform LDS u16 base

  const int nk = K >> 6;

#define STAGE(c, kt)                                                            \
  do {                                                                          \
    const u16* a_ = gA + (size_t)(kt) * 64;                                     \
    const u16* b_ = gB + (size_t)(kt) * 64;                                     \
    _Pragma("unroll")                                                           \
    for (int k_ = 0; k_ < 4; ++k_)                                              \
      gload16(a_ + (size_t)k_ * 64 * K, &As[c][lbase + k_ * 512 * 8]);          \
    _Pragma("unroll")                                                           \
    for (int k_ = 0; k_ < NREP; ++k_)                                           \
      gload16(b_ + (size_t)k_ * 64 * K, &Bs[c][lbase + k_ * 512 * 8]);          \
  } while (0)

  STAGE(0, 0);
  STAGE(1, 1);
  asm volatile("s_waitcnt vmcnt(%0)" :: "i"(TLOADS) : "memory");
  __builtin_amdgcn_sched_barrier(0);
  __builtin_amdgcn_s_barrier();
  __builtin_amdgcn_sched_barrier(0);

  const int arow = wm * 128 + l15;                 // + m*16
  const int bcl  = wn * (BN / 4) + l15;            // + n*16
  const int kk0  = l4 << 3;                        // u16 k-offset, ks1 adds 32
  const int aswz = (arow & 7) << 3;
  const int bswz = (bcl & 7) << 3;

  for (int t = 0; t < nk; ++t) {
    const int c = t & 1;
    const u16* as = As[c];
    const u16* bs = Bs[c];
    bf16x8 af[8], bf[NREP];

    // ---- ks0 ----
#pragma unroll
    for (int m = 0; m < 8; ++m)
      af[m] = *(const bf16x8*)&as[(arow + m * 16) * 64 + (kk0 ^ aswz)];
#pragma unroll
    for (int n = 0; n < NREP; ++n)
      bf[n] = *(const bf16x8*)&bs[(bcl + n * 16) * 64 + (kk0 ^ bswz)];
    __builtin_amdgcn_s_setprio(1);
#pragma unroll
    for (int m = 0; m < 8; ++m)
#pragma unroll
      for (int n = 0; n < NREP; ++n)
        acc[m][n] = __builtin_amdgcn_mfma_f32_16x16x32_bf16(af[m], bf[n], acc[m][n], 0, 0, 0);
    __builtin_amdgcn_s_setprio(0);

    // ---- ks1 reads ----
#pragma unroll
    for (int m = 0; m < 8; ++m)
      af[m] = *(const bf16x8*)&as[(arow + m * 16) * 64 + ((kk0 + 32) ^ aswz)];
#pragma unroll
    for (int n = 0; n < NREP; ++n)
      bf[n] = *(const bf16x8*)&bs[(bcl + n * 16) * 64 + ((kk0 + 32) ^ bswz)];
    asm volatile("s_waitcnt lgkmcnt(0)" ::: "memory");
    __builtin_amdgcn_sched_barrier(0);
    __builtin_amdgcn_s_barrier();                  // all waves done reading buf c
    __builtin_amdgcn_sched_barrier(0);

    if (t + 2 < nk) STAGE(c, t + 2);               // fire & forget into freed buf

    __builtin_amdgcn_s_setprio(1);
#pragma unroll
    for (int m = 0; m < 8; ++m)
#pragma unroll
      for (int n = 0; n < NREP; ++n)
        acc[m][n] = __builtin_amdgcn_mfma_f32_16x16x32_bf16(af[m], bf[n], acc[m][n], 0, 0, 0);
    __builtin_amdgcn_s_setprio(0);

    if (t + 2 < nk) {                              // counted: tile t+1 landed,
      asm volatile("s_waitcnt vmcnt(%0)" :: "i"(TLOADS) : "memory");  // t+2 flying
    } else {
      asm volatile("s_waitcnt vmcnt(0)" ::: "memory");
    }
    __builtin_amdgcn_sched_barrier(0);
    __builtin_amdgcn_s_barrier();
    __builtin_amdgcn_sched_barrier(0);
  }
#undef STAGE

  // C/D layout (verified): col = lane&15, row = (lane>>4)*4 + reg
  const int rowb = brow + wm * 128 + (l4 << 2);
  const int colb = bcol + wn * (BN / 4) + l15;
#pragma unroll
  for (int n = 0; n < NREP; ++n) {
    const int col = colb + n * 16;
    float bv = 0.f;
    if (EPI != 0) bv = bias[col];
#pragma unroll
    for (int m = 0; m < 8; ++m) {
#pragma unroll
      for (int j = 0; j < 4; ++j) {
        const int row = rowb + m * 16 + j;
        const float v = acc[m][n][j];
        if (EPI == 0) {
          ((u16*)Cv)[(size_t)row * N + col] = f2bf(v);
        } else if (EPI == 1) {
          ((float*)Cv)[(size_t)row * N + col] = v + bv + res[(size_t)row * N + col];
        } else {
          const float t2 = v + bv;
          const float gl = 0.5f * t2 * (1.0f + erff(t2 * 0.70710678118654752f));
          ((u16*)Cv)[(size_t)row * N + col] = f2bf(gl);
        }
      }
    }
  }
}

// ---------------- causal flash attention v5b (unchanged from R6) -------------
__global__ __launch_bounds__(512) void attn_fwd(const u16* __restrict__ qkv,
                                                const u16* __restrict__ Vt,
                                                u16* __restrict__ attn) {
  __shared__ __align__(16) u16 Ks[64 * 72];       // [kv][d], pad 8
  __shared__ __align__(16) u16 Vs[64 * 72];       // [d][kv], pad 8
  __shared__ __align__(16) u16 Ps[8 * 16 * 72];   // per-wave P^T-source [q][kv]
  const int tid = threadIdx.x, lane = tid & 63, wid = tid >> 6;
  const int l4 = lane >> 4, l15 = lane & 15;
  const int bh = blockIdx.y, b = bh >> 4, h = bh & 15;
  const size_t bt0 = (size_t)b * SEQ;
  u16* Pw = &Ps[wid * 16 * 72];

  const int sr = tid >> 3;
  const int sc0 = (tid & 7) << 3;                 // u16 col: 0,8,...,56
  const u16* kbase = qkv + bt0 * 3072 + 1024 + h * 64;
  const u16* vbase = Vt + (size_t)bh * 64 * SEQ;
  const f32x4 z4 = {0.f, 0.f, 0.f, 0.f};

#pragma unroll
  for (int ph = 0; ph < 2; ++ph) {
    const int Qb = ((ph == 0) ? (int)blockIdx.x : 15 - (int)blockIdx.x) << 7;
    const int qw = Qb + wid * 16;
    const int qlane = qw + l15;

    const u16* qp = qkv + (bt0 + qlane) * 3072 + h * 64 + (l4 << 3);
    const bf16x8 aq0 = *(const bf16x8*)qp;
    const bf16x8 aq1 = *(const bf16x8*)(qp + 32);

    f32x4 o[4];
#pragma unroll
    for (int dt = 0; dt < 4; ++dt) o[dt] = z4;
    float mrun = -1e30f, lrun = 0.f;

    bf16x8 kp = *(const bf16x8*)(kbase + (size_t)sr * 3072 + sc0);
    bf16x8 vp = *(const bf16x8*)(vbase + (size_t)sr * SEQ + sc0);

    const int jend = Qb + 128;
    for (int j0 = 0; j0 < jend; j0 += 64) {
      __syncthreads();
      *(bf16x8*)&Ks[sr * 72 + sc0] = kp;
      *(bf16x8*)&Vs[sr * 72 + sc0] = vp;
      __syncthreads();

      if (j0 + 64 < jend) {
        kp = *(const bf16x8*)(kbase + (size_t)(j0 + 64 + sr) * 3072 + sc0);
        vp = *(const bf16x8*)(vbase + (size_t)sr * SEQ + j0 + 64 + sc0);
      }

      if (j0 > qw + 15) continue;
      const int nt = min(4, ((qw + 15 - j0) >> 4) + 1);

      f32x4 s[4];
#pragma unroll
      for (int t = 0; t < 4; ++t) {
        if (t < nt) {
          const bf16x8 ak0 = *(const bf16x8*)&Ks[(t * 16 + l15) * 72 + (l4 << 3)];
          const bf16x8 ak1 = *(const bf16x8*)&Ks[(t * 16 + l15) * 72 + 32 + (l4 << 3)];
          f32x4 a = z4;
          a = __builtin_amdgcn_mfma_f32_16x16x32_bf16(ak0, aq0, a, 0, 0, 0);
          a = __builtin_amdgcn_mfma_f32_16x16x32_bf16(ak1, aq1, a, 0, 0, 0);
          s[t] = a;
        }
      }

      float mt = -1e30f;
#pragma unroll
      for (int t = 0; t < 4; ++t) {
        if (t < nt) {
          if (j0 + t * 16 + 15 > qw) {
            const int kvb = j0 + t * 16 + (l4 << 2);
#pragma unroll
            for (int j = 0; j < 4; ++j)
              if (kvb + j > qlane) s[t][j] = -1e30f;
          }
          mt = fmaxf(mt, fmaxf(fmaxf(s[t][0], s[t][1]), fmaxf(s[t][2], s[t][3])));
        }
      }
      mt = fmaxf(mt, __shfl_xor(mt, 16));
      mt = fmaxf(mt, __shfl_xor(mt, 32));

      const bool skip = __all(mt <= mrun + 44.0f);
      float scq = 1.0f;
      if (!skip) {
        const float mn = fmaxf(mrun, mt);
        scq = exp2f((mrun - mn) * ATT_C);
        mrun = mn;
      }
      const float mc = mrun * ATT_C;

      float ls = 0.f;
      uint2 pw[4];
#pragma unroll
      for (int t = 0; t < 4; ++t) {
        if (t < nt) {
          const float p0 = exp2f(__builtin_fmaf(s[t][0], ATT_C, -mc));
          const float p1 = exp2f(__builtin_fmaf(s[t][1], ATT_C, -mc));
          const float p2 = exp2f(__builtin_fmaf(s[t][2], ATT_C, -mc));
          const float p3 = exp2f(__builtin_fmaf(s[t][3], ATT_C, -mc));
          ls += (p0 + p1) + (p2 + p3);
          pw[t].x = cvtpk(p0, p1);
          pw[t].y = cvtpk(p2, p3);
        } else {
          pw[t].x = 0u; pw[t].y = 0u;
        }
      }
#pragma unroll
      for (int t = 0; t < 4; ++t)
        *(uint2*)&Pw[l15 * 72 + t * 16 + (l4 << 2)] = pw[t];

      ls += __shfl_xor(ls, 16);
      ls += __shfl_xor(ls, 32);

      if (!skip) {
        lrun = lrun * scq + ls;
#pragma unroll
        for (int dt = 0; dt < 4; ++dt)
#pragma unroll
          for (int j = 0; j < 4; ++j) o[dt][j] *= scq;
      } else {
        lrun += ls;
      }

      const int nc = (nt + 1) >> 1;
#pragma unroll
      for (int c = 0; c < 2; ++c) {
        if (c < nc) {
          const bf16x8 ap = *(const bf16x8*)&Pw[l15 * 72 + c * 32 + (l4 << 3)];
#pragma unroll
          for (int dt = 0; dt < 4; ++dt) {
            const bf16x8 bv = *(const bf16x8*)&Vs[(dt * 16 + l15) * 72 + c * 32 + (l4 << 3)];
            o[dt] = __builtin_amdgcn_mfma_f32_16x16x32_bf16(bv, ap, o[dt], 0, 0, 0);
          }
        }
      }
    }

    const float rl = 1.0f / lrun;
#pragma unroll
    for (int dt = 0; dt < 4; ++dt) {
      uint2 w;
      w.x = cvtpk(o[dt][0] * rl, o[dt][1] * rl);
      w.y = cvtpk(o[dt][2] * rl, o[dt][3] * rl);
      *(uint2*)&Pw[l15 * 72 + dt * 16 + (l4 << 2)] = w;
    }
#pragma unroll
    for (int rep = 0; rep < 2; ++rep) {
      const int unit = rep * 64 + lane;
      const int r = unit >> 3, c = unit & 7;
      const bf16x8 v = *(const bf16x8*)&Pw[r * 72 + c * 8];
      *(bf16x8*)&attn[(bt0 + qw + r) * EMBED + h * 64 + c * 8] = v;
    }
  }
}

// ---------------- driver ------------------------------------------------------
extern "C" void kernel_launch(void* const* d_in, const int* in_sizes, int n_in,
                              void* d_out, int out_size, void* d_ws, size_t ws_size,
                              hipStream_t stream) {
  const float* x   = (const float*)d_in[0];
  const float* Wq  = (const float*)d_in[1];
  const float* Wk  = (const float*)d_in[2];
  const float* Wv  = (const float*)d_in[3];
  const float* Wo  = (const float*)d_in[4];
  const float* bo  = (const float*)d_in[5];
  const float* W1  = (const float*)d_in[6];
  const float* b1  = (const float*)d_in[7];
  const float* W2  = (const float*)d_in[8];
  const float* b2  = (const float*)d_in[9];
  const float* g1  = (const float*)d_in[10];
  const float* be1 = (const float*)d_in[11];
  const float* g2  = (const float*)d_in[12];
  const float* be2 = (const float*)d_in[13];

  char* ws = (char*)d_ws;
  u16* wqkv_t = (u16*)(ws + 0);                 // [3072][1024] bf16   6 MB
  u16* wo_t   = (u16*)(ws + 6291456);           // [1024][1024]        2 MB
  u16* w1_t   = (u16*)(ws + 8388608);           // [4096][1024]        8 MB
  u16* w2_t   = (u16*)(ws + 16777216);          // [1024][4096]        8 MB
  u16* hbuf   = (u16*)(ws + 25165824);          // LN out, reused     16 MB
  u16* qkv    = (u16*)(ws + 41943040);          // [8192][3072]       48 MB
  u16* ff1    = (u16*)(ws + 41943040);          // overlaps qkv+Vt    64 MB
  u16* vt     = (u16*)(ws + 92274688);          // [64*64][2048]      16 MB
  u16* attnb  = (u16*)(ws + 109051904);         // [8192][1024]       16 MB
  float* x2   = (float*)(ws + 125829120);       // fp32 residual      32 MB
  float* outp = (float*)d_out;

  dim3 blk(256);
  wtrans<<<dim3(32, 32),  blk, 0, stream>>>(Wq, wqkv_t,               1024, 1024);
  wtrans<<<dim3(32, 32),  blk, 0, stream>>>(Wk, wqkv_t + 1024 * 1024, 1024, 1024);
  wtrans<<<dim3(32, 32),  blk, 0, stream>>>(Wv, wqkv_t + 2048 * 1024, 1024, 1024);
  wtrans<<<dim3(32, 32),  blk, 0, stream>>>(Wo, wo_t,                 1024, 1024);
  wtrans<<<dim3(128, 32), blk, 0, stream>>>(W1, w1_t,                 1024, 4096);
  wtrans<<<dim3(32, 128), blk, 0, stream>>>(W2, w2_t,                 4096, 1024);

  ln_kernel<<<dim3(8192), blk, 0, stream>>>(x, g1, be1, hbuf);
  gemm2<4, 0><<<dim3(12, 32), dim3(512), 0, stream>>>(hbuf, wqkv_t, qkv, nullptr, nullptr,
                                                      8192, 3072, 1024);
  vtrans<<<dim3(64, 128), blk, 0, stream>>>(qkv, vt);
  attn_fwd<<<dim3(8, 64), dim3(512), 0, stream>>>(qkv, vt, attnb);
  gemm2<2, 1><<<dim3(8, 32), dim3(512), 0, stream>>>(attnb, wo_t, x2, bo, x,
                                                     8192, 1024, 1024);
  ln_kernel<<<dim3(8192), blk, 0, stream>>>(x2, g2, be2, hbuf);
  gemm2<4, 2><<<dim3(16, 32), dim3(512), 0, stream>>>(hbuf, w1_t, ff1, b1, nullptr,
                                                      8192, 4096, 1024);
  gemm2<2, 1><<<dim3(8, 32), dim3(512), 0, stream>>>(ff1, w2_t, outp, b2, x2,
                                                     8192, 1024, 4096);
}